// Round 1
// baseline (5399.470 us; speedup 1.0000x reference)
//
#include <hip/hip_runtime.h>
#include <hip/hip_bf16.h>

// SparseMoE: router -> per-expert grouped MFMA GEMMs (bf16) -> residual+LN.
// B=4 T=2048 D=1024 E=8 FF=4096 K=2 ; N = 8192 tokens.
// ws layout (bytes), total ~118 MB:
//   [0)            x_bf16      N*D*2    = 16 MiB
//   [16777216)     H           N*FF*2   = 64 MiB   (per-expert reuse, worst case)
//   [83886080)     out_acc     N*D*4    = 32 MiB   (fp32 accumulator, zeroed)
//   [117440512)    tlist       E*N*4
//   [117702656)    wlist       E*N*4
//   [117964800)    counts      E*4
//   [117964832)    psum        E*4
//   [117964864)    lse2        4

#define NTOK 8192
#define DIM  1024
#define NEXP 8
#define NFF  4096
#define KSEL 2

typedef __attribute__((ext_vector_type(8))) short short8;
typedef __attribute__((ext_vector_type(4))) float floatx4;
typedef unsigned short u16;
typedef unsigned int u32;

#define XB_OFF    0ull
#define H_OFF     16777216ull
#define OACC_OFF  83886080ull
#define TLIST_OFF 117440512ull
#define WLIST_OFF 117702656ull
#define CNT_OFF   117964800ull
#define PSUM_OFF  117964832ull
#define LSE2_OFF  117964864ull

__device__ __forceinline__ u16 f2bf(float f) {
  u32 u = __float_as_uint(f);
  u32 r = u + 0x7fffu + ((u >> 16) & 1u);   // round-to-nearest-even
  return (u16)(r >> 16);
}
__device__ __forceinline__ u32 pk2(float a, float b) {
  return (u32)f2bf(a) | ((u32)f2bf(b) << 16);
}

// ---------------- Router: logits, softmax, top-2, aux stats, x->bf16 ----------------
__global__ void router_k(const float* __restrict__ x,
                         const float* __restrict__ gW,
                         u16* __restrict__ xb,
                         int* __restrict__ tlist,
                         float* __restrict__ wlist,
                         int* __restrict__ counts,
                         float* __restrict__ psum,
                         float* __restrict__ lse2sum) {
  __shared__ float sp[NEXP];
  __shared__ float slse2;
  if (threadIdx.x < NEXP) sp[threadIdx.x] = 0.f;
  if (threadIdx.x == NEXP) slse2 = 0.f;
  __syncthreads();

  const int lane = threadIdx.x & 63;
  const int wv   = threadIdx.x >> 6;
  const int t    = blockIdx.x * 4 + wv;   // grid = N/4 exactly

  const float* xr = x + (size_t)t * DIM + lane * 16;
  float xv[16];
#pragma unroll
  for (int i = 0; i < 4; ++i) {
    float4 v = ((const float4*)xr)[i];
    xv[4*i+0] = v.x; xv[4*i+1] = v.y; xv[4*i+2] = v.z; xv[4*i+3] = v.w;
  }
  // fused fp32 -> bf16 copy of x
  u16* xbp = xb + (size_t)t * DIM + lane * 16;
  uint4 pa, pb;
  pa.x = pk2(xv[0], xv[1]);   pa.y = pk2(xv[2], xv[3]);
  pa.z = pk2(xv[4], xv[5]);   pa.w = pk2(xv[6], xv[7]);
  pb.x = pk2(xv[8], xv[9]);   pb.y = pk2(xv[10], xv[11]);
  pb.z = pk2(xv[12], xv[13]); pb.w = pk2(xv[14], xv[15]);
  ((uint4*)xbp)[0] = pa;
  ((uint4*)xbp)[1] = pb;

  float lg[NEXP];
#pragma unroll
  for (int e = 0; e < NEXP; ++e) {
    const float* wr = gW + (size_t)e * DIM + lane * 16;
    float s = 0.f;
#pragma unroll
    for (int i = 0; i < 4; ++i) {
      float4 v = ((const float4*)wr)[i];
      s = fmaf(xv[4*i+0], v.x, s);
      s = fmaf(xv[4*i+1], v.y, s);
      s = fmaf(xv[4*i+2], v.z, s);
      s = fmaf(xv[4*i+3], v.w, s);
    }
    lg[e] = s;
  }
#pragma unroll
  for (int off = 32; off > 0; off >>= 1) {
#pragma unroll
    for (int e = 0; e < NEXP; ++e)
      lg[e] += __shfl_xor(lg[e], off, 64);
  }
  float mx = lg[0];
#pragma unroll
  for (int e = 1; e < NEXP; ++e) mx = fmaxf(mx, lg[e]);
  float p[NEXP];
  float se = 0.f;
#pragma unroll
  for (int e = 0; e < NEXP; ++e) { p[e] = expf(lg[e] - mx); se += p[e]; }
  float inv = 1.f / se;
#pragma unroll
  for (int e = 0; e < NEXP; ++e) p[e] *= inv;
  float lse = mx + logf(se);

  if (lane == 0) {
    // top-2, ties -> lower index (matches jax top_k)
    int i0 = 0;
#pragma unroll
    for (int e = 1; e < NEXP; ++e) if (p[e] > p[i0]) i0 = e;
    int i1 = (i0 == 0) ? 1 : 0;
#pragma unroll
    for (int e = 0; e < NEXP; ++e) if (e != i0 && p[e] > p[i1]) i1 = e;
    float v0 = p[i0], v1 = p[i1];
    float s2 = v0 + v1 + 1e-6f;
    int pos0 = atomicAdd(&counts[i0], 1);
    tlist[i0 * NTOK + pos0] = t;
    wlist[i0 * NTOK + pos0] = v0 / s2;
    int pos1 = atomicAdd(&counts[i1], 1);
    tlist[i1 * NTOK + pos1] = t;
    wlist[i1 * NTOK + pos1] = v1 / s2;
#pragma unroll
    for (int e = 0; e < NEXP; ++e) atomicAdd(&sp[e], p[e]);
    atomicAdd(&slse2, lse * lse);
  }
  __syncthreads();
  if (threadIdx.x < NEXP) atomicAdd(&psum[threadIdx.x], sp[threadIdx.x]);
  if (threadIdx.x == NEXP) atomicAdd(lse2sum, slse2);
}

// ---------------- Pass A: H = silu(X Wg^T) * (X Wu^T) for one expert ----------------
// tile 128 tokens x 128 FF, BK=64, 4 waves each doing a 64x64 subtile of BOTH matmuls.
__global__ __launch_bounds__(256, 2) void expertA_k(
    const u16* __restrict__ xb,
    const float* __restrict__ Wg,
    const float* __restrict__ Wu,
    const int* __restrict__ tlist,
    const int* __restrict__ counts,
    u16* __restrict__ H,
    int e) {
  const int cnt = counts[e];
  const int m0 = blockIdx.x * 128;
  if (m0 >= cnt) return;
  const int n0 = blockIdx.y * 128;

  __shared__ u16 smem[3 * 128 * 72];   // A | Wg | Wu tiles, row stride 72 (+8 pad)
  u16* sA = smem;
  u16* sG = smem + 128 * 72;
  u16* sU = smem + 2 * 128 * 72;

  const int tid  = threadIdx.x;
  const int lane = tid & 63;
  const int wv   = tid >> 6;
  const int mo   = (wv & 1) * 64;
  const int no   = (wv >> 1) * 64;
  const int l15  = lane & 15;
  const int quad = lane >> 4;

  floatx4 zero = {0.f, 0.f, 0.f, 0.f};
  floatx4 accG[4][4], accU[4][4];
#pragma unroll
  for (int i = 0; i < 4; ++i)
#pragma unroll
    for (int j = 0; j < 4; ++j) { accG[i][j] = zero; accU[i][j] = zero; }

  const size_t wbase = (size_t)e * NFF * DIM;
  const int* tl = tlist + e * NTOK;

  for (int kc = 0; kc < DIM; kc += 64) {
    // stage A tile: gathered token rows, bf16, 8-elem chunks
    for (int c = tid; c < 1024; c += 256) {
      int r = c >> 3, col = (c & 7) * 8;
      int row = m0 + r; if (row > cnt - 1) row = cnt - 1;  // clamp: dup rows, masked at store
      int tok = tl[row];
      *(uint4*)(sA + r * 72 + col) = *(const uint4*)(xb + (size_t)tok * DIM + kc + col);
    }
    // stage Wg/Wu tiles: fp32 -> bf16 convert
    for (int c = tid; c < 2048; c += 256) {
      int r = c >> 4, col = (c & 15) * 4;
      size_t gi = wbase + (size_t)(n0 + r) * DIM + kc + col;
      float4 g = *(const float4*)(Wg + gi);
      float4 u = *(const float4*)(Wu + gi);
      uint2 pg; pg.x = pk2(g.x, g.y); pg.y = pk2(g.z, g.w);
      uint2 pu; pu.x = pk2(u.x, u.y); pu.y = pk2(u.z, u.w);
      *(uint2*)(sG + r * 72 + col) = pg;
      *(uint2*)(sU + r * 72 + col) = pu;
    }
    __syncthreads();
#pragma unroll
    for (int ks = 0; ks < 64; ks += 32) {
      const int kb = ks + quad * 8;
      short8 av[4], bg[4], bu[4];
#pragma unroll
      for (int i = 0; i < 4; ++i) {
        av[i] = *(const short8*)(sA + (mo + i * 16 + l15) * 72 + kb);
        bg[i] = *(const short8*)(sG + (no + i * 16 + l15) * 72 + kb);
        bu[i] = *(const short8*)(sU + (no + i * 16 + l15) * 72 + kb);
      }
#pragma unroll
      for (int mi = 0; mi < 4; ++mi)
#pragma unroll
        for (int ni = 0; ni < 4; ++ni) {
          accG[mi][ni] = __builtin_amdgcn_mfma_f32_16x16x32_bf16(av[mi], bg[ni], accG[mi][ni], 0, 0, 0);
          accU[mi][ni] = __builtin_amdgcn_mfma_f32_16x16x32_bf16(av[mi], bu[ni], accU[mi][ni], 0, 0, 0);
        }
    }
    __syncthreads();
  }

  // silu(g)*u -> bf16 via LDS (row stride 136) then vectorized global store
  u16* sH = smem;
#pragma unroll
  for (int mi = 0; mi < 4; ++mi)
#pragma unroll
    for (int ni = 0; ni < 4; ++ni)
#pragma unroll
      for (int i = 0; i < 4; ++i) {
        float g = accG[mi][ni][i];
        float u = accU[mi][ni][i];
        float h = (g / (1.f + __expf(-g))) * u;
        int r  = mo + mi * 16 + quad * 4 + i;   // C/D: row = quad*4+reg
        int cc = no + ni * 16 + l15;            //      col = lane&15
        sH[r * 136 + cc] = f2bf(h);
      }
  __syncthreads();
  for (int c = tid; c < 2048; c += 256) {
    int r = c >> 4, col = (c & 15) * 8;
    int row = m0 + r;
    if (row < cnt)
      *(uint4*)(H + (size_t)row * NFF + n0 + col) = *(const uint4*)(sH + r * 136 + col);
  }
}

// ---------------- Pass B: out_acc[tok] += gate * (H Wd^T) for one expert ----------------
__global__ __launch_bounds__(256, 2) void expertB_k(
    const u16* __restrict__ H,
    const float* __restrict__ Wd,
    const int* __restrict__ tlist,
    const float* __restrict__ wlist,
    const int* __restrict__ counts,
    float* __restrict__ oacc,
    int e) {
  const int cnt = counts[e];
  const int m0 = blockIdx.x * 128;
  if (m0 >= cnt) return;
  const int n0 = blockIdx.y * 128;

  __shared__ u16 smem[2 * 128 * 72];
  __shared__ int   sTok[128];
  __shared__ float sWt[128];
  u16* sA = smem;
  u16* sB = smem + 128 * 72;

  const int tid = threadIdx.x;
  if (tid < 128) {
    int row = m0 + tid; if (row > cnt - 1) row = cnt - 1;
    sTok[tid] = tlist[e * NTOK + row];
    sWt[tid]  = wlist[e * NTOK + row];
  }

  const int lane = tid & 63;
  const int wv   = tid >> 6;
  const int mo   = (wv & 1) * 64;
  const int no   = (wv >> 1) * 64;
  const int l15  = lane & 15;
  const int quad = lane >> 4;

  floatx4 zero = {0.f, 0.f, 0.f, 0.f};
  floatx4 acc[4][4];
#pragma unroll
  for (int i = 0; i < 4; ++i)
#pragma unroll
    for (int j = 0; j < 4; ++j) acc[i][j] = zero;

  const size_t wbase = (size_t)e * DIM * NFF;

  for (int kc = 0; kc < NFF; kc += 64) {
    for (int c = tid; c < 1024; c += 256) {
      int r = c >> 3, col = (c & 7) * 8;
      *(uint4*)(sA + r * 72 + col) = *(const uint4*)(H + (size_t)(m0 + r) * NFF + kc + col);
    }
    for (int c = tid; c < 2048; c += 256) {
      int r = c >> 4, col = (c & 15) * 4;
      float4 v = *(const float4*)(Wd + wbase + (size_t)(n0 + r) * NFF + kc + col);
      uint2 pv; pv.x = pk2(v.x, v.y); pv.y = pk2(v.z, v.w);
      *(uint2*)(sB + r * 72 + col) = pv;
    }
    __syncthreads();
#pragma unroll
    for (int ks = 0; ks < 64; ks += 32) {
      const int kb = ks + quad * 8;
      short8 av[4], bv[4];
#pragma unroll
      for (int i = 0; i < 4; ++i) {
        av[i] = *(const short8*)(sA + (mo + i * 16 + l15) * 72 + kb);
        bv[i] = *(const short8*)(sB + (no + i * 16 + l15) * 72 + kb);
      }
#pragma unroll
      for (int mi = 0; mi < 4; ++mi)
#pragma unroll
        for (int ni = 0; ni < 4; ++ni)
          acc[mi][ni] = __builtin_amdgcn_mfma_f32_16x16x32_bf16(av[mi], bv[ni], acc[mi][ni], 0, 0, 0);
    }
    __syncthreads();
  }

  // scaled scatter-accumulate (no atomics needed: expert passes serialize on stream,
  // each token appears at most once per expert, col-blocks disjoint)
#pragma unroll
  for (int mi = 0; mi < 4; ++mi)
#pragma unroll
    for (int ni = 0; ni < 4; ++ni)
#pragma unroll
      for (int i = 0; i < 4; ++i) {
        int r = mo + mi * 16 + quad * 4 + i;
        int grow = m0 + r;
        if (grow < cnt) {
          int cc = n0 + no + ni * 16 + l15;
          float* dst = oacc + (size_t)sTok[r] * DIM + cc;
          *dst += sWt[r] * acc[mi][ni][i];
        }
      }
}

// ---------------- Residual + LayerNorm ----------------
__global__ void ln_k(const float* __restrict__ x,
                     const float* __restrict__ oacc,
                     const float* __restrict__ gamma,
                     const float* __restrict__ beta,
                     float* __restrict__ out) {
  const int lane = threadIdx.x & 63;
  const int wv   = threadIdx.x >> 6;
  const int t    = blockIdx.x * 4 + wv;
  const size_t base = (size_t)t * DIM + lane * 16;
  float y[16];
  float s = 0.f, s2 = 0.f;
#pragma unroll
  for (int i = 0; i < 4; ++i) {
    float4 a = ((const float4*)(x + base))[i];
    float4 b = ((const float4*)(oacc + base))[i];
    float c0 = a.x + b.x, c1 = a.y + b.y, c2 = a.z + b.z, c3 = a.w + b.w;
    y[4*i+0] = c0; y[4*i+1] = c1; y[4*i+2] = c2; y[4*i+3] = c3;
    s  += c0 + c1 + c2 + c3;
    s2 += c0*c0 + c1*c1 + c2*c2 + c3*c3;
  }
#pragma unroll
  for (int off = 32; off > 0; off >>= 1) {
    s  += __shfl_xor(s, off, 64);
    s2 += __shfl_xor(s2, off, 64);
  }
  const float mean = s * (1.f / DIM);
  const float var  = s2 * (1.f / DIM) - mean * mean;
  const float rstd = rsqrtf(var + 1e-5f);
#pragma unroll
  for (int i = 0; i < 4; ++i) {
    float4 g  = ((const float4*)(gamma + lane * 16))[i];
    float4 bb = ((const float4*)(beta  + lane * 16))[i];
    float4 o;
    o.x = (y[4*i+0] - mean) * rstd * g.x + bb.x;
    o.y = (y[4*i+1] - mean) * rstd * g.y + bb.y;
    o.z = (y[4*i+2] - mean) * rstd * g.z + bb.z;
    o.w = (y[4*i+3] - mean) * rstd * g.w + bb.w;
    ((float4*)(out + base))[i] = o;
  }
}

// ---------------- Aux loss finalize ----------------
__global__ void aux_k(const int* __restrict__ counts,
                      const float* __restrict__ psum,
                      const float* __restrict__ lse2sum,
                      float* __restrict__ out) {
  if (threadIdx.x == 0 && blockIdx.x == 0) {
    float lb = 0.f;
    for (int e = 0; e < NEXP; ++e) {
      float fi = (float)counts[e] / (float)(NTOK * KSEL);
      float Pi = psum[e] / (float)NTOK;
      lb += fi * Pi;
    }
    lb *= (float)NEXP;
    float z = (*lse2sum / (float)NTOK) * 1e-3f;
    out[(size_t)NTOK * DIM] = 0.01f * (lb + z);
  }
}

extern "C" void kernel_launch(void* const* d_in, const int* in_sizes, int n_in,
                              void* d_out, int out_size, void* d_ws, size_t ws_size,
                              hipStream_t stream) {
  const float* x     = (const float*)d_in[0];
  const float* gW    = (const float*)d_in[1];
  const float* Wg    = (const float*)d_in[2];
  const float* Wu    = (const float*)d_in[3];
  const float* Wd    = (const float*)d_in[4];
  const float* gamma = (const float*)d_in[5];
  const float* beta  = (const float*)d_in[6];
  float* out = (float*)d_out;
  char* ws = (char*)d_ws;

  u16*   xb    = (u16*)(ws + XB_OFF);
  u16*   H     = (u16*)(ws + H_OFF);
  float* oacc  = (float*)(ws + OACC_OFF);
  int*   tlist = (int*)(ws + TLIST_OFF);
  float* wlist = (float*)(ws + WLIST_OFF);
  int*   counts = (int*)(ws + CNT_OFF);
  float* psum   = (float*)(ws + PSUM_OFF);
  float* lse2   = (float*)(ws + LSE2_OFF);

  // zero the small accumulators (counts+psum+lse2, contiguous 68 B) and out accumulator
  hipMemsetAsync(ws + CNT_OFF, 0, 68, stream);
  hipMemsetAsync(ws + OACC_OFF, 0, (size_t)NTOK * DIM * 4, stream);

  router_k<<<NTOK / 4, 256, 0, stream>>>(x, gW, xb, tlist, wlist, counts, psum, lse2);

  for (int e = 0; e < NEXP; ++e) {
    expertA_k<<<dim3(64, 32), 256, 0, stream>>>(xb, Wg, Wu, tlist, counts, H, e);
    expertB_k<<<dim3(64, 8), 256, 0, stream>>>(H, Wd, tlist, wlist, counts, oacc, e);
  }

  ln_k<<<NTOK / 4, 256, 0, stream>>>(x, oacc, gamma, beta, out);
  aux_k<<<1, 64, 0, stream>>>(counts, psum, lse2, out);
}

// Round 2
// 3201.061 us; speedup vs baseline: 1.6868x; 1.6868x over previous
//
#include <hip/hip_runtime.h>
#include <hip/hip_bf16.h>

// SparseMoE: router -> merged-expert MFMA GEMMs (bf16, FF split in halves) -> residual+LN.
// B=4 T=2048 D=1024 E=8 FF=4096 K=2 ; N = 8192 tokens, total expert-rows = N*K = 16384.
// ws layout (bytes), total ~118 MB (known-good budget):
//   [0)           x_bf16   N*D*2            = 16 MiB
//   [16777216)    H        16384*2048*2     = 64 MiB  (compact slot rows, half of FF)
//   [83886080)    oacc     N*D*4            = 32 MiB  (fp32 accumulator, atomicAdd)
//   [117440512)   tlist    E*N*4
//   [117702656)   wlist    E*N*4
//   [117964800)   counts   E*4  | psum E*4 | lse2 4 | offsets E*4

#define NTOK 8192
#define DIM  1024
#define NEXP 8
#define NFF  4096
#define FFH  2048     // half of FF per A/B pass
#define KSEL 2

typedef __attribute__((ext_vector_type(8))) short short8;
typedef __attribute__((ext_vector_type(4))) float floatx4;
typedef unsigned short u16;
typedef unsigned int u32;

#define XB_OFF    0ull
#define H_OFF     16777216ull
#define OACC_OFF  83886080ull
#define TLIST_OFF 117440512ull
#define WLIST_OFF 117702656ull
#define CNT_OFF   117964800ull
#define PSUM_OFF  117964832ull
#define LSE2_OFF  117964864ull
#define OFFS_OFF  117964896ull

__device__ __forceinline__ u16 f2bf(float f) {
  u32 u = __float_as_uint(f);
  u32 r = u + 0x7fffu + ((u >> 16) & 1u);   // round-to-nearest-even
  return (u16)(r >> 16);
}
__device__ __forceinline__ u32 pk2(float a, float b) {
  return (u32)f2bf(a) | ((u32)f2bf(b) << 16);
}

// ---------------- Router: logits, softmax, top-2, aux stats, x->bf16 ----------------
__global__ void router_k(const float* __restrict__ x,
                         const float* __restrict__ gW,
                         u16* __restrict__ xb,
                         int* __restrict__ tlist,
                         float* __restrict__ wlist,
                         int* __restrict__ counts,
                         float* __restrict__ psum,
                         float* __restrict__ lse2sum) {
  __shared__ float sp[NEXP];
  __shared__ float slse2;
  if (threadIdx.x < NEXP) sp[threadIdx.x] = 0.f;
  if (threadIdx.x == NEXP) slse2 = 0.f;
  __syncthreads();

  const int lane = threadIdx.x & 63;
  const int wv   = threadIdx.x >> 6;
  const int t    = blockIdx.x * 4 + wv;   // grid = N/4 exactly

  const float* xr = x + (size_t)t * DIM + lane * 16;
  float xv[16];
#pragma unroll
  for (int i = 0; i < 4; ++i) {
    float4 v = ((const float4*)xr)[i];
    xv[4*i+0] = v.x; xv[4*i+1] = v.y; xv[4*i+2] = v.z; xv[4*i+3] = v.w;
  }
  // fused fp32 -> bf16 copy of x
  u16* xbp = xb + (size_t)t * DIM + lane * 16;
  uint4 pa, pb;
  pa.x = pk2(xv[0], xv[1]);   pa.y = pk2(xv[2], xv[3]);
  pa.z = pk2(xv[4], xv[5]);   pa.w = pk2(xv[6], xv[7]);
  pb.x = pk2(xv[8], xv[9]);   pb.y = pk2(xv[10], xv[11]);
  pb.z = pk2(xv[12], xv[13]); pb.w = pk2(xv[14], xv[15]);
  ((uint4*)xbp)[0] = pa;
  ((uint4*)xbp)[1] = pb;

  float lg[NEXP];
#pragma unroll
  for (int e = 0; e < NEXP; ++e) {
    const float* wr = gW + (size_t)e * DIM + lane * 16;
    float s = 0.f;
#pragma unroll
    for (int i = 0; i < 4; ++i) {
      float4 v = ((const float4*)wr)[i];
      s = fmaf(xv[4*i+0], v.x, s);
      s = fmaf(xv[4*i+1], v.y, s);
      s = fmaf(xv[4*i+2], v.z, s);
      s = fmaf(xv[4*i+3], v.w, s);
    }
    lg[e] = s;
  }
#pragma unroll
  for (int off = 32; off > 0; off >>= 1) {
#pragma unroll
    for (int e = 0; e < NEXP; ++e)
      lg[e] += __shfl_xor(lg[e], off, 64);
  }
  float mx = lg[0];
#pragma unroll
  for (int e = 1; e < NEXP; ++e) mx = fmaxf(mx, lg[e]);
  float p[NEXP];
  float se = 0.f;
#pragma unroll
  for (int e = 0; e < NEXP; ++e) { p[e] = expf(lg[e] - mx); se += p[e]; }
  float inv = 1.f / se;
#pragma unroll
  for (int e = 0; e < NEXP; ++e) p[e] *= inv;
  float lse = mx + logf(se);

  if (lane == 0) {
    // top-2, ties -> lower index (matches jax top_k)
    int i0 = 0;
#pragma unroll
    for (int e = 1; e < NEXP; ++e) if (p[e] > p[i0]) i0 = e;
    int i1 = (i0 == 0) ? 1 : 0;
#pragma unroll
    for (int e = 0; e < NEXP; ++e) if (e != i0 && p[e] > p[i1]) i1 = e;
    float v0 = p[i0], v1 = p[i1];
    float s2 = v0 + v1 + 1e-6f;
    int pos0 = atomicAdd(&counts[i0], 1);
    tlist[i0 * NTOK + pos0] = t;
    wlist[i0 * NTOK + pos0] = v0 / s2;
    int pos1 = atomicAdd(&counts[i1], 1);
    tlist[i1 * NTOK + pos1] = t;
    wlist[i1 * NTOK + pos1] = v1 / s2;
#pragma unroll
    for (int e = 0; e < NEXP; ++e) atomicAdd(&sp[e], p[e]);
    atomicAdd(&slse2, lse * lse);
  }
  __syncthreads();
  if (threadIdx.x < NEXP) atomicAdd(&psum[threadIdx.x], sp[threadIdx.x]);
  if (threadIdx.x == NEXP) atomicAdd(lse2sum, slse2);
}

// ---------------- offsets: prefix-sum of counts (compact H row base per expert) ----------------
__global__ void offsets_k(const int* __restrict__ counts, int* __restrict__ offsets) {
  if (threadIdx.x == 0 && blockIdx.x == 0) {
    int s = 0;
    for (int e = 0; e < NEXP; ++e) { offsets[e] = s; s += counts[e]; }
  }
}

// ---------------- Pass A (merged experts): H = silu(X Wg^T) * (X Wu^T), half of FF ----------------
// blockIdx.x encodes (expert, m-tile): e = bx>>6, m0 = (bx&63)*128. Inactive tiles exit.
// blockIdx.y covers FFH/128 = 16 n-tiles of the current FF half.
__global__ __launch_bounds__(256, 2) void expertA_k(
    const u16* __restrict__ xb,
    const float* __restrict__ Wg,
    const float* __restrict__ Wu,
    const int* __restrict__ tlist,
    const int* __restrict__ counts,
    const int* __restrict__ offsets,
    u16* __restrict__ H,         // [16384, FFH] compact slot rows
    int ffbase) {
  const int e   = blockIdx.x >> 6;
  const int m0  = (blockIdx.x & 63) * 128;
  const int cnt = counts[e];
  if (m0 >= cnt) return;
  const int n0 = ffbase + blockIdx.y * 128;   // row of Wg/Wu
  const int hc0 = blockIdx.y * 128;           // col in H half-buffer
  const int hrow0 = offsets[e];

  __shared__ u16 smem[3 * 128 * 72];   // A | Wg | Wu tiles, row stride 72 (+8 pad)
  u16* sA = smem;
  u16* sG = smem + 128 * 72;
  u16* sU = smem + 2 * 128 * 72;

  const int tid  = threadIdx.x;
  const int lane = tid & 63;
  const int wv   = tid >> 6;
  const int mo   = (wv & 1) * 64;
  const int no   = (wv >> 1) * 64;
  const int l15  = lane & 15;
  const int quad = lane >> 4;

  floatx4 zero = {0.f, 0.f, 0.f, 0.f};
  floatx4 accG[4][4], accU[4][4];
#pragma unroll
  for (int i = 0; i < 4; ++i)
#pragma unroll
    for (int j = 0; j < 4; ++j) { accG[i][j] = zero; accU[i][j] = zero; }

  const size_t wbase = (size_t)e * NFF * DIM;
  const int* tl = tlist + e * NTOK;

  for (int kc = 0; kc < DIM; kc += 64) {
    // stage A tile: gathered token rows, bf16
    for (int c = tid; c < 1024; c += 256) {
      int r = c >> 3, col = (c & 7) * 8;
      int row = m0 + r; if (row > cnt - 1) row = cnt - 1;  // clamp: dup rows, masked at store
      int tok = tl[row];
      *(uint4*)(sA + r * 72 + col) = *(const uint4*)(xb + (size_t)tok * DIM + kc + col);
    }
    // stage Wg/Wu tiles: fp32 -> bf16 convert
    for (int c = tid; c < 2048; c += 256) {
      int r = c >> 4, col = (c & 15) * 4;
      size_t gi = wbase + (size_t)(n0 + r) * DIM + kc + col;
      float4 g = *(const float4*)(Wg + gi);
      float4 u = *(const float4*)(Wu + gi);
      uint2 pg; pg.x = pk2(g.x, g.y); pg.y = pk2(g.z, g.w);
      uint2 pu; pu.x = pk2(u.x, u.y); pu.y = pk2(u.z, u.w);
      *(uint2*)(sG + r * 72 + col) = pg;
      *(uint2*)(sU + r * 72 + col) = pu;
    }
    __syncthreads();
#pragma unroll
    for (int ks = 0; ks < 64; ks += 32) {
      const int kb = ks + quad * 8;
      short8 av[4], bg[4], bu[4];
#pragma unroll
      for (int i = 0; i < 4; ++i) {
        av[i] = *(const short8*)(sA + (mo + i * 16 + l15) * 72 + kb);
        bg[i] = *(const short8*)(sG + (no + i * 16 + l15) * 72 + kb);
        bu[i] = *(const short8*)(sU + (no + i * 16 + l15) * 72 + kb);
      }
#pragma unroll
      for (int mi = 0; mi < 4; ++mi)
#pragma unroll
        for (int ni = 0; ni < 4; ++ni) {
          accG[mi][ni] = __builtin_amdgcn_mfma_f32_16x16x32_bf16(av[mi], bg[ni], accG[mi][ni], 0, 0, 0);
          accU[mi][ni] = __builtin_amdgcn_mfma_f32_16x16x32_bf16(av[mi], bu[ni], accU[mi][ni], 0, 0, 0);
        }
    }
    __syncthreads();
  }

  // silu(g)*u -> bf16 via LDS (row stride 136) then vectorized global store
  u16* sH = smem;
#pragma unroll
  for (int mi = 0; mi < 4; ++mi)
#pragma unroll
    for (int ni = 0; ni < 4; ++ni)
#pragma unroll
      for (int i = 0; i < 4; ++i) {
        float g = accG[mi][ni][i];
        float u = accU[mi][ni][i];
        float h = (g / (1.f + __expf(-g))) * u;
        int r  = mo + mi * 16 + quad * 4 + i;   // C/D: row = quad*4+reg
        int cc = no + ni * 16 + l15;            //      col = lane&15
        sH[r * 136 + cc] = f2bf(h);
      }
  __syncthreads();
  for (int c = tid; c < 2048; c += 256) {
    int r = c >> 4, col = (c & 15) * 8;
    int row = m0 + r;
    if (row < cnt)
      *(uint4*)(H + (size_t)(hrow0 + row) * FFH + hc0 + col) = *(const uint4*)(sH + r * 136 + col);
  }
}

// ---------------- Pass B (merged experts): oacc[tok] += gate * (H Wd^T), half-FF K ----------------
__global__ __launch_bounds__(256, 2) void expertB_k(
    const u16* __restrict__ H,          // [16384, FFH]
    const float* __restrict__ Wd,
    const int* __restrict__ tlist,
    const float* __restrict__ wlist,
    const int* __restrict__ counts,
    const int* __restrict__ offsets,
    float* __restrict__ oacc,
    int ffbase) {
  const int e   = blockIdx.x >> 6;
  const int m0  = (blockIdx.x & 63) * 128;
  const int cnt = counts[e];
  if (m0 >= cnt) return;
  const int n0 = blockIdx.y * 128;
  const int hrow0 = offsets[e];

  __shared__ u16 smem[2 * 128 * 72];
  __shared__ int   sTok[128];
  __shared__ float sWt[128];
  u16* sA = smem;
  u16* sB = smem + 128 * 72;

  const int tid = threadIdx.x;
  if (tid < 128) {
    int row = m0 + tid; if (row > cnt - 1) row = cnt - 1;
    sTok[tid] = tlist[e * NTOK + row];
    sWt[tid]  = wlist[e * NTOK + row];
  }

  const int lane = tid & 63;
  const int wv   = tid >> 6;
  const int mo   = (wv & 1) * 64;
  const int no   = (wv >> 1) * 64;
  const int l15  = lane & 15;
  const int quad = lane >> 4;

  floatx4 zero = {0.f, 0.f, 0.f, 0.f};
  floatx4 acc[4][4];
#pragma unroll
  for (int i = 0; i < 4; ++i)
#pragma unroll
    for (int j = 0; j < 4; ++j) acc[i][j] = zero;

  const size_t wbase = (size_t)e * DIM * NFF;

  for (int kc = 0; kc < FFH; kc += 64) {
    for (int c = tid; c < 1024; c += 256) {
      int r = c >> 3, col = (c & 7) * 8;
      int row = m0 + r; if (row > cnt - 1) row = cnt - 1;
      *(uint4*)(sA + r * 72 + col) = *(const uint4*)(H + (size_t)(hrow0 + row) * FFH + kc + col);
    }
    for (int c = tid; c < 2048; c += 256) {
      int r = c >> 4, col = (c & 15) * 4;
      float4 v = *(const float4*)(Wd + wbase + (size_t)(n0 + r) * NFF + ffbase + kc + col);
      uint2 pv; pv.x = pk2(v.x, v.y); pv.y = pk2(v.z, v.w);
      *(uint2*)(sB + r * 72 + col) = pv;
    }
    __syncthreads();
#pragma unroll
    for (int ks = 0; ks < 64; ks += 32) {
      const int kb = ks + quad * 8;
      short8 av[4], bv[4];
#pragma unroll
      for (int i = 0; i < 4; ++i) {
        av[i] = *(const short8*)(sA + (mo + i * 16 + l15) * 72 + kb);
        bv[i] = *(const short8*)(sB + (no + i * 16 + l15) * 72 + kb);
      }
#pragma unroll
      for (int mi = 0; mi < 4; ++mi)
#pragma unroll
        for (int ni = 0; ni < 4; ++ni)
          acc[mi][ni] = __builtin_amdgcn_mfma_f32_16x16x32_bf16(av[mi], bv[ni], acc[mi][ni], 0, 0, 0);
    }
    __syncthreads();
  }

  // scaled scatter-accumulate: atomicAdd (a token can be hit by 2 experts in one dispatch)
#pragma unroll
  for (int mi = 0; mi < 4; ++mi)
#pragma unroll
    for (int ni = 0; ni < 4; ++ni)
#pragma unroll
      for (int i = 0; i < 4; ++i) {
        int r = mo + mi * 16 + quad * 4 + i;
        int grow = m0 + r;
        if (grow < cnt) {
          int cc = n0 + no + ni * 16 + l15;
          atomicAdd(oacc + (size_t)sTok[r] * DIM + cc, sWt[r] * acc[mi][ni][i]);
        }
      }
}

// ---------------- Residual + LayerNorm ----------------
__global__ void ln_k(const float* __restrict__ x,
                     const float* __restrict__ oacc,
                     const float* __restrict__ gamma,
                     const float* __restrict__ beta,
                     float* __restrict__ out) {
  const int lane = threadIdx.x & 63;
  const int wv   = threadIdx.x >> 6;
  const int t    = blockIdx.x * 4 + wv;
  const size_t base = (size_t)t * DIM + lane * 16;
  float y[16];
  float s = 0.f, s2 = 0.f;
#pragma unroll
  for (int i = 0; i < 4; ++i) {
    float4 a = ((const float4*)(x + base))[i];
    float4 b = ((const float4*)(oacc + base))[i];
    float c0 = a.x + b.x, c1 = a.y + b.y, c2 = a.z + b.z, c3 = a.w + b.w;
    y[4*i+0] = c0; y[4*i+1] = c1; y[4*i+2] = c2; y[4*i+3] = c3;
    s  += c0 + c1 + c2 + c3;
    s2 += c0*c0 + c1*c1 + c2*c2 + c3*c3;
  }
#pragma unroll
  for (int off = 32; off > 0; off >>= 1) {
    s  += __shfl_xor(s, off, 64);
    s2 += __shfl_xor(s2, off, 64);
  }
  const float mean = s * (1.f / DIM);
  const float var  = s2 * (1.f / DIM) - mean * mean;
  const float rstd = rsqrtf(var + 1e-5f);
#pragma unroll
  for (int i = 0; i < 4; ++i) {
    float4 g  = ((const float4*)(gamma + lane * 16))[i];
    float4 bb = ((const float4*)(beta  + lane * 16))[i];
    float4 o;
    o.x = (y[4*i+0] - mean) * rstd * g.x + bb.x;
    o.y = (y[4*i+1] - mean) * rstd * g.y + bb.y;
    o.z = (y[4*i+2] - mean) * rstd * g.z + bb.z;
    o.w = (y[4*i+3] - mean) * rstd * g.w + bb.w;
    ((float4*)(out + base))[i] = o;
  }
}

// ---------------- Aux loss finalize ----------------
__global__ void aux_k(const int* __restrict__ counts,
                      const float* __restrict__ psum,
                      const float* __restrict__ lse2sum,
                      float* __restrict__ out) {
  if (threadIdx.x == 0 && blockIdx.x == 0) {
    float lb = 0.f;
    for (int e = 0; e < NEXP; ++e) {
      float fi = (float)counts[e] / (float)(NTOK * KSEL);
      float Pi = psum[e] / (float)NTOK;
      lb += fi * Pi;
    }
    lb *= (float)NEXP;
    float z = (*lse2sum / (float)NTOK) * 1e-3f;
    out[(size_t)NTOK * DIM] = 0.01f * (lb + z);
  }
}

extern "C" void kernel_launch(void* const* d_in, const int* in_sizes, int n_in,
                              void* d_out, int out_size, void* d_ws, size_t ws_size,
                              hipStream_t stream) {
  const float* x     = (const float*)d_in[0];
  const float* gW    = (const float*)d_in[1];
  const float* Wg    = (const float*)d_in[2];
  const float* Wu    = (const float*)d_in[3];
  const float* Wd    = (const float*)d_in[4];
  const float* gamma = (const float*)d_in[5];
  const float* beta  = (const float*)d_in[6];
  float* out = (float*)d_out;
  char* ws = (char*)d_ws;

  u16*   xb     = (u16*)(ws + XB_OFF);
  u16*   H      = (u16*)(ws + H_OFF);
  float* oacc   = (float*)(ws + OACC_OFF);
  int*   tlist  = (int*)(ws + TLIST_OFF);
  float* wlist  = (float*)(ws + WLIST_OFF);
  int*   counts = (int*)(ws + CNT_OFF);
  float* psum   = (float*)(ws + PSUM_OFF);
  float* lse2   = (float*)(ws + LSE2_OFF);
  int*   offs   = (int*)(ws + OFFS_OFF);

  // zero the small accumulators (counts+psum+lse2, contiguous 68 B) and out accumulator
  hipMemsetAsync(ws + CNT_OFF, 0, 68, stream);
  hipMemsetAsync(ws + OACC_OFF, 0, (size_t)NTOK * DIM * 4, stream);

  router_k<<<NTOK / 4, 256, 0, stream>>>(x, gW, xb, tlist, wlist, counts, psum, lse2);
  offsets_k<<<1, 64, 0, stream>>>(counts, offs);

  // FF half 1
  expertA_k<<<dim3(NEXP * 64, FFH / 128), 256, 0, stream>>>(xb, Wg, Wu, tlist, counts, offs, H, 0);
  expertB_k<<<dim3(NEXP * 64, DIM / 128), 256, 0, stream>>>(H, Wd, tlist, wlist, counts, offs, oacc, 0);
  // FF half 2
  expertA_k<<<dim3(NEXP * 64, FFH / 128), 256, 0, stream>>>(xb, Wg, Wu, tlist, counts, offs, H, FFH);
  expertB_k<<<dim3(NEXP * 64, DIM / 128), 256, 0, stream>>>(H, Wd, tlist, wlist, counts, offs, oacc, FFH);

  ln_k<<<NTOK / 4, 256, 0, stream>>>(x, oacc, gamma, beta, out);
  aux_k<<<1, 64, 0, stream>>>(counts, psum, lse2, out);
}

// Round 3
// 2404.357 us; speedup vs baseline: 2.2457x; 1.3314x over previous
//
#include <hip/hip_runtime.h>
#include <hip/hip_bf16.h>

// SparseMoE: router -> bf16 weight pre-convert -> merged-expert MFMA GEMMs with
// global_load_lds staging (m97 structure) -> residual+LN.
// B=4 T=2048 D=1024 E=8 FF=4096 K=2 ; N=8192 tokens, expert-rows = 16384.
//
// BIG path ws layout (needs ~240.5 MiB):
//   [0)          x_bf16   16 MiB
//   [16M)        H        16384*1024*2 = 32 MiB (quarter-FF slot rows)
//   [48M)        Wg_bf16  64 MiB
//   [112M)       Wu_bf16  64 MiB
//   [176M)       Wd_bf16  64 MiB
//   [240M)       tlist/wlist/counters/offsets
//   oacc = d_out (fp32 atomicAdd accumulator, LN runs in-place)
// FALLBACK path (ws >= 118 MiB, round-2 proven): fp32 weights converted in-kernel.

#define NTOK 8192
#define DIM  1024
#define NEXP 8
#define NFF  4096
#define FFQ  1024     // quarter of FF per A/B pass (big path)
#define FFH  2048     // half of FF per A/B pass (fallback path)
#define KSEL 2

typedef __attribute__((ext_vector_type(8))) short short8;
typedef __attribute__((ext_vector_type(4))) float floatx4;
typedef unsigned short u16;
typedef unsigned int u32;

// big-path ws offsets (bytes)
#define B_XB    0ull
#define B_HBUF  16777216ull
#define B_WG    50331648ull
#define B_WU    117440512ull
#define B_WD    184549376ull
#define B_TL    251658240ull
#define B_WL    251920384ull
#define B_CNT   252182528ull
#define B_PSUM  252182560ull
#define B_LSE2  252182592ull
#define B_OFFS  252182624ull
#define B_NEED  252182656ull

// fallback ws offsets (round-2 layout)
#define F_XB    0ull
#define F_HBUF  16777216ull
#define F_OACC  83886080ull
#define F_TL    117440512ull
#define F_WL    117702656ull
#define F_CNT   117964800ull
#define F_PSUM  117964832ull
#define F_LSE2  117964864ull
#define F_OFFS  117964896ull

__device__ __forceinline__ u16 f2bf(float f) {
  u32 u = __float_as_uint(f);
  u32 r = u + 0x7fffu + ((u >> 16) & 1u);   // round-to-nearest-even
  return (u16)(r >> 16);
}
__device__ __forceinline__ u32 pk2(float a, float b) {
  return (u32)f2bf(a) | ((u32)f2bf(b) << 16);
}

// async global->LDS DMA, 16 B per lane; LDS base must be wave-uniform.
typedef const __attribute__((address_space(1))) u32 gas_u32;
typedef __attribute__((address_space(3))) u32 las_u32;
__device__ __forceinline__ void dma16(const u16* g, u16* l) {
  __builtin_amdgcn_global_load_lds((gas_u32*)g, (las_u32*)l, 16, 0, 0);
}

// ---------------- Router: logits, softmax, top-2, aux stats, x->bf16 ----------------
__global__ void router_k(const float* __restrict__ x,
                         const float* __restrict__ gW,
                         u16* __restrict__ xb,
                         int* __restrict__ tlist,
                         float* __restrict__ wlist,
                         int* __restrict__ counts,
                         float* __restrict__ psum,
                         float* __restrict__ lse2sum) {
  __shared__ float sp[NEXP];
  __shared__ float slse2;
  if (threadIdx.x < NEXP) sp[threadIdx.x] = 0.f;
  if (threadIdx.x == NEXP) slse2 = 0.f;
  __syncthreads();

  const int lane = threadIdx.x & 63;
  const int wv   = threadIdx.x >> 6;
  const int t    = blockIdx.x * 4 + wv;   // grid = N/4 exactly

  const float* xr = x + (size_t)t * DIM + lane * 16;
  float xv[16];
#pragma unroll
  for (int i = 0; i < 4; ++i) {
    float4 v = ((const float4*)xr)[i];
    xv[4*i+0] = v.x; xv[4*i+1] = v.y; xv[4*i+2] = v.z; xv[4*i+3] = v.w;
  }
  u16* xbp = xb + (size_t)t * DIM + lane * 16;
  uint4 pa, pb;
  pa.x = pk2(xv[0], xv[1]);   pa.y = pk2(xv[2], xv[3]);
  pa.z = pk2(xv[4], xv[5]);   pa.w = pk2(xv[6], xv[7]);
  pb.x = pk2(xv[8], xv[9]);   pb.y = pk2(xv[10], xv[11]);
  pb.z = pk2(xv[12], xv[13]); pb.w = pk2(xv[14], xv[15]);
  ((uint4*)xbp)[0] = pa;
  ((uint4*)xbp)[1] = pb;

  float lg[NEXP];
#pragma unroll
  for (int e = 0; e < NEXP; ++e) {
    const float* wr = gW + (size_t)e * DIM + lane * 16;
    float s = 0.f;
#pragma unroll
    for (int i = 0; i < 4; ++i) {
      float4 v = ((const float4*)wr)[i];
      s = fmaf(xv[4*i+0], v.x, s);
      s = fmaf(xv[4*i+1], v.y, s);
      s = fmaf(xv[4*i+2], v.z, s);
      s = fmaf(xv[4*i+3], v.w, s);
    }
    lg[e] = s;
  }
#pragma unroll
  for (int off = 32; off > 0; off >>= 1) {
#pragma unroll
    for (int e = 0; e < NEXP; ++e)
      lg[e] += __shfl_xor(lg[e], off, 64);
  }
  float mx = lg[0];
#pragma unroll
  for (int e = 1; e < NEXP; ++e) mx = fmaxf(mx, lg[e]);
  float p[NEXP];
  float se = 0.f;
#pragma unroll
  for (int e = 0; e < NEXP; ++e) { p[e] = expf(lg[e] - mx); se += p[e]; }
  float inv = 1.f / se;
#pragma unroll
  for (int e = 0; e < NEXP; ++e) p[e] *= inv;
  float lse = mx + logf(se);

  if (lane == 0) {
    int i0 = 0;
#pragma unroll
    for (int e = 1; e < NEXP; ++e) if (p[e] > p[i0]) i0 = e;
    int i1 = (i0 == 0) ? 1 : 0;
#pragma unroll
    for (int e = 0; e < NEXP; ++e) if (e != i0 && p[e] > p[i1]) i1 = e;
    float v0 = p[i0], v1 = p[i1];
    float s2 = v0 + v1 + 1e-6f;
    int pos0 = atomicAdd(&counts[i0], 1);
    tlist[i0 * NTOK + pos0] = t;
    wlist[i0 * NTOK + pos0] = v0 / s2;
    int pos1 = atomicAdd(&counts[i1], 1);
    tlist[i1 * NTOK + pos1] = t;
    wlist[i1 * NTOK + pos1] = v1 / s2;
#pragma unroll
    for (int e = 0; e < NEXP; ++e) atomicAdd(&sp[e], p[e]);
    atomicAdd(&slse2, lse * lse);
  }
  __syncthreads();
  if (threadIdx.x < NEXP) atomicAdd(&psum[threadIdx.x], sp[threadIdx.x]);
  if (threadIdx.x == NEXP) atomicAdd(lse2sum, slse2);
}

// ---------------- offsets: prefix-sum of counts ----------------
__global__ void offsets_k(const int* __restrict__ counts, int* __restrict__ offsets) {
  if (threadIdx.x == 0 && blockIdx.x == 0) {
    int s = 0;
    for (int e = 0; e < NEXP; ++e) { offsets[e] = s; s += counts[e]; }
  }
}

// ---------------- fp32 -> bf16 bulk convert (one-time, memory-bound) ----------------
__global__ void cvt_k(const float* __restrict__ s, u16* __restrict__ d, long n) {
  long i = ((long)blockIdx.x * 256 + threadIdx.x) * 8;
  if (i >= n) return;
  float4 a = *(const float4*)(s + i);
  float4 b = *(const float4*)(s + i + 4);
  uint4 o;
  o.x = pk2(a.x, a.y); o.y = pk2(a.z, a.w);
  o.z = pk2(b.x, b.y); o.w = pk2(b.z, b.w);
  *(uint4*)(d + i) = o;
}

// ================= BIG PATH: m97-style kernels, bf16 weights, async staging =================

// Pass A: H = silu(X Wg^T) * (X Wu^T), quarter of FF.
// blockIdx.x = (e<<6)|mtile ; blockIdx.y = n-tile within FF quarter.
__global__ __launch_bounds__(256, 3) void expA_k(
    const u16* __restrict__ xb,
    const u16* __restrict__ Wg,
    const u16* __restrict__ Wu,
    const int* __restrict__ tlist,
    const int* __restrict__ counts,
    const int* __restrict__ offsets,
    u16* __restrict__ H,          // [16384, FFQ] compact slot rows
    int ffbase) {
  const int e   = blockIdx.x >> 6;
  const int m0  = (blockIdx.x & 63) * 128;
  const int cnt = counts[e];
  if (m0 >= cnt) return;
  const int n0  = ffbase + blockIdx.y * 128;
  const int hc0 = blockIdx.y * 128;
  const int hrow0 = offsets[e];

  __shared__ u16 smem[3 * 128 * 64];   // A | G | U tiles, unpadded (DMA layout)
  u16* sA = smem;
  u16* sG = smem + 8192;
  u16* sU = smem + 16384;

  const int tid  = threadIdx.x;
  const int lane = tid & 63;
  const int wv   = tid >> 6;
  const int l15  = lane & 15;
  const int quad = lane >> 4;
  const int mo   = (wv & 1) * 64;
  const int no   = (wv >> 1) * 64;
  const int srow = lane >> 3;          // row within 8-row DMA group
  const int scol = (lane & 7) * 8;     // element col of this lane's 16B

  // per-lane global bases (fixed across K), wave-uniform LDS bases
  const u16* gA[4];
  size_t wOff[4];
#pragma unroll
  for (int j = 0; j < 4; ++j) {
    int r = 32 * wv + 8 * j + srow;
    int row = m0 + r; if (row > cnt - 1) row = cnt - 1;   // clamp: dup rows, masked at store
    int tok = tlist[e * NTOK + row];
    gA[j]  = xb + (size_t)tok * DIM + scol;
    wOff[j] = (size_t)e * NFF * DIM + (size_t)(n0 + r) * DIM + scol;
  }

  floatx4 zero = {0.f, 0.f, 0.f, 0.f};
  floatx4 accG[4][4], accU[4][4];
#pragma unroll
  for (int i = 0; i < 4; ++i)
#pragma unroll
    for (int j = 0; j < 4; ++j) { accG[i][j] = zero; accU[i][j] = zero; }

  for (int kc = 0; kc < DIM; kc += 64) {
#pragma unroll
    for (int j = 0; j < 4; ++j) {
      u16* lb = smem + (32 * wv + 8 * j) * 64;   // wave-uniform
      dma16(gA[j] + kc,      lb);
      dma16(Wg + wOff[j] + kc, lb + 8192);
      dma16(Wu + wOff[j] + kc, lb + 16384);
    }
    __syncthreads();   // drains vmcnt (DMA) before reads
#pragma unroll
    for (int ks = 0; ks < 64; ks += 32) {
      const int kb = ks + quad * 8;
      short8 av[4], bg[4], bu[4];
#pragma unroll
      for (int i = 0; i < 4; ++i) {
        av[i] = *(const short8*)(sA + (mo + i * 16 + l15) * 64 + kb);
        bg[i] = *(const short8*)(sG + (no + i * 16 + l15) * 64 + kb);
        bu[i] = *(const short8*)(sU + (no + i * 16 + l15) * 64 + kb);
      }
#pragma unroll
      for (int mi = 0; mi < 4; ++mi)
#pragma unroll
        for (int ni = 0; ni < 4; ++ni) {
          accG[mi][ni] = __builtin_amdgcn_mfma_f32_16x16x32_bf16(av[mi], bg[ni], accG[mi][ni], 0, 0, 0);
          accU[mi][ni] = __builtin_amdgcn_mfma_f32_16x16x32_bf16(av[mi], bu[ni], accU[mi][ni], 0, 0, 0);
        }
    }
    __syncthreads();   // all reads done before next DMA overwrites
  }

  // silu(g)*u -> bf16 via LDS (stride 136) then vectorized store
  u16* sH = smem;      // 128*136 u16 = 34 KB <= 48 KB
#pragma unroll
  for (int mi = 0; mi < 4; ++mi)
#pragma unroll
    for (int ni = 0; ni < 4; ++ni)
#pragma unroll
      for (int i = 0; i < 4; ++i) {
        float g = accG[mi][ni][i];
        float u = accU[mi][ni][i];
        float h = (g / (1.f + __expf(-g))) * u;
        int r  = mo + mi * 16 + quad * 4 + i;   // C/D: row = quad*4+reg
        int cc = no + ni * 16 + l15;            //      col = lane&15
        sH[r * 136 + cc] = f2bf(h);
      }
  __syncthreads();
  for (int c = tid; c < 2048; c += 256) {
    int r = c >> 4, col = (c & 15) * 8;
    int row = m0 + r;
    if (row < cnt)
      *(uint4*)(H + (size_t)(hrow0 + row) * FFQ + hc0 + col) = *(const uint4*)(sH + r * 136 + col);
  }
}

// Pass B: oacc[tok] += gate * (H Wd^T), quarter-FF K.
__global__ __launch_bounds__(256, 4) void expB_k(
    const u16* __restrict__ H,           // [16384, FFQ]
    const u16* __restrict__ Wd,
    const int* __restrict__ tlist,
    const float* __restrict__ wlist,
    const int* __restrict__ counts,
    const int* __restrict__ offsets,
    float* __restrict__ oacc,
    int ffbase) {
  const int e   = blockIdx.x >> 6;
  const int m0  = (blockIdx.x & 63) * 128;
  const int cnt = counts[e];
  if (m0 >= cnt) return;
  const int n0 = blockIdx.y * 128;
  const int hrow0 = offsets[e];

  __shared__ u16 smem2[2 * 128 * 64];
  __shared__ int   sTok[128];
  __shared__ float sWt[128];
  u16* sA = smem2;
  u16* sB = smem2 + 8192;

  const int tid = threadIdx.x;
  if (tid < 128) {
    int row = m0 + tid; if (row > cnt - 1) row = cnt - 1;
    sTok[tid] = tlist[e * NTOK + row];
    sWt[tid]  = wlist[e * NTOK + row];
  }

  const int lane = tid & 63;
  const int wv   = tid >> 6;
  const int l15  = lane & 15;
  const int quad = lane >> 4;
  const int mo   = (wv & 1) * 64;
  const int no   = (wv >> 1) * 64;
  const int srow = lane >> 3;
  const int scol = (lane & 7) * 8;

  const u16* gH[4];
  size_t wOff[4];
#pragma unroll
  for (int j = 0; j < 4; ++j) {
    int r = 32 * wv + 8 * j + srow;
    int row = m0 + r; if (row > cnt - 1) row = cnt - 1;
    gH[j]  = H + (size_t)(hrow0 + row) * FFQ + scol;
    wOff[j] = (size_t)e * DIM * NFF + (size_t)(n0 + r) * NFF + ffbase + scol;
  }

  floatx4 zero = {0.f, 0.f, 0.f, 0.f};
  floatx4 acc[4][4];
#pragma unroll
  for (int i = 0; i < 4; ++i)
#pragma unroll
    for (int j = 0; j < 4; ++j) acc[i][j] = zero;

  for (int kc = 0; kc < FFQ; kc += 64) {
#pragma unroll
    for (int j = 0; j < 4; ++j) {
      u16* lb = smem2 + (32 * wv + 8 * j) * 64;
      dma16(gH[j] + kc,        lb);
      dma16(Wd + wOff[j] + kc, lb + 8192);
    }
    __syncthreads();
#pragma unroll
    for (int ks = 0; ks < 64; ks += 32) {
      const int kb = ks + quad * 8;
      short8 av[4], bv[4];
#pragma unroll
      for (int i = 0; i < 4; ++i) {
        av[i] = *(const short8*)(sA + (mo + i * 16 + l15) * 64 + kb);
        bv[i] = *(const short8*)(sB + (no + i * 16 + l15) * 64 + kb);
      }
#pragma unroll
      for (int mi = 0; mi < 4; ++mi)
#pragma unroll
        for (int ni = 0; ni < 4; ++ni)
          acc[mi][ni] = __builtin_amdgcn_mfma_f32_16x16x32_bf16(av[mi], bv[ni], acc[mi][ni], 0, 0, 0);
    }
    __syncthreads();
  }

  // scatter-accumulate: atomicAdd (token can be hit by 2 experts per dispatch)
#pragma unroll
  for (int mi = 0; mi < 4; ++mi)
#pragma unroll
    for (int ni = 0; ni < 4; ++ni)
#pragma unroll
      for (int i = 0; i < 4; ++i) {
        int r = mo + mi * 16 + quad * 4 + i;
        int grow = m0 + r;
        if (grow < cnt) {
          int cc = n0 + no + ni * 16 + l15;
          atomicAdd(oacc + (size_t)sTok[r] * DIM + cc, sWt[r] * acc[mi][ni][i]);
        }
      }
}

// ================= FALLBACK PATH (round-2 proven kernels, fp32 weights) =================

__global__ __launch_bounds__(256, 2) void expertA_fb(
    const u16* __restrict__ xb,
    const float* __restrict__ Wg,
    const float* __restrict__ Wu,
    const int* __restrict__ tlist,
    const int* __restrict__ counts,
    const int* __restrict__ offsets,
    u16* __restrict__ H,         // [16384, FFH]
    int ffbase) {
  const int e   = blockIdx.x >> 6;
  const int m0  = (blockIdx.x & 63) * 128;
  const int cnt = counts[e];
  if (m0 >= cnt) return;
  const int n0 = ffbase + blockIdx.y * 128;
  const int hc0 = blockIdx.y * 128;
  const int hrow0 = offsets[e];

  __shared__ u16 smem[3 * 128 * 72];
  u16* sA = smem;
  u16* sG = smem + 128 * 72;
  u16* sU = smem + 2 * 128 * 72;

  const int tid  = threadIdx.x;
  const int lane = tid & 63;
  const int wv   = tid >> 6;
  const int mo   = (wv & 1) * 64;
  const int no   = (wv >> 1) * 64;
  const int l15  = lane & 15;
  const int quad = lane >> 4;

  floatx4 zero = {0.f, 0.f, 0.f, 0.f};
  floatx4 accG[4][4], accU[4][4];
#pragma unroll
  for (int i = 0; i < 4; ++i)
#pragma unroll
    for (int j = 0; j < 4; ++j) { accG[i][j] = zero; accU[i][j] = zero; }

  const size_t wbase = (size_t)e * NFF * DIM;
  const int* tl = tlist + e * NTOK;

  for (int kc = 0; kc < DIM; kc += 64) {
    for (int c = tid; c < 1024; c += 256) {
      int r = c >> 3, col = (c & 7) * 8;
      int row = m0 + r; if (row > cnt - 1) row = cnt - 1;
      int tok = tl[row];
      *(uint4*)(sA + r * 72 + col) = *(const uint4*)(xb + (size_t)tok * DIM + kc + col);
    }
    for (int c = tid; c < 2048; c += 256) {
      int r = c >> 4, col = (c & 15) * 4;
      size_t gi = wbase + (size_t)(n0 + r) * DIM + kc + col;
      float4 g = *(const float4*)(Wg + gi);
      float4 u = *(const float4*)(Wu + gi);
      uint2 pg; pg.x = pk2(g.x, g.y); pg.y = pk2(g.z, g.w);
      uint2 pu; pu.x = pk2(u.x, u.y); pu.y = pk2(u.z, u.w);
      *(uint2*)(sG + r * 72 + col) = pg;
      *(uint2*)(sU + r * 72 + col) = pu;
    }
    __syncthreads();
#pragma unroll
    for (int ks = 0; ks < 64; ks += 32) {
      const int kb = ks + quad * 8;
      short8 av[4], bg[4], bu[4];
#pragma unroll
      for (int i = 0; i < 4; ++i) {
        av[i] = *(const short8*)(sA + (mo + i * 16 + l15) * 72 + kb);
        bg[i] = *(const short8*)(sG + (no + i * 16 + l15) * 72 + kb);
        bu[i] = *(const short8*)(sU + (no + i * 16 + l15) * 72 + kb);
      }
#pragma unroll
      for (int mi = 0; mi < 4; ++mi)
#pragma unroll
        for (int ni = 0; ni < 4; ++ni) {
          accG[mi][ni] = __builtin_amdgcn_mfma_f32_16x16x32_bf16(av[mi], bg[ni], accG[mi][ni], 0, 0, 0);
          accU[mi][ni] = __builtin_amdgcn_mfma_f32_16x16x32_bf16(av[mi], bu[ni], accU[mi][ni], 0, 0, 0);
        }
    }
    __syncthreads();
  }

  u16* sH = smem;
#pragma unroll
  for (int mi = 0; mi < 4; ++mi)
#pragma unroll
    for (int ni = 0; ni < 4; ++ni)
#pragma unroll
      for (int i = 0; i < 4; ++i) {
        float g = accG[mi][ni][i];
        float u = accU[mi][ni][i];
        float h = (g / (1.f + __expf(-g))) * u;
        int r  = mo + mi * 16 + quad * 4 + i;
        int cc = no + ni * 16 + l15;
        sH[r * 136 + cc] = f2bf(h);
      }
  __syncthreads();
  for (int c = tid; c < 2048; c += 256) {
    int r = c >> 4, col = (c & 15) * 8;
    int row = m0 + r;
    if (row < cnt)
      *(uint4*)(H + (size_t)(hrow0 + row) * FFH + hc0 + col) = *(const uint4*)(sH + r * 136 + col);
  }
}

__global__ __launch_bounds__(256, 2) void expertB_fb(
    const u16* __restrict__ H,          // [16384, FFH]
    const float* __restrict__ Wd,
    const int* __restrict__ tlist,
    const float* __restrict__ wlist,
    const int* __restrict__ counts,
    const int* __restrict__ offsets,
    float* __restrict__ oacc,
    int ffbase) {
  const int e   = blockIdx.x >> 6;
  const int m0  = (blockIdx.x & 63) * 128;
  const int cnt = counts[e];
  if (m0 >= cnt) return;
  const int n0 = blockIdx.y * 128;
  const int hrow0 = offsets[e];

  __shared__ u16 smem[2 * 128 * 72];
  __shared__ int   sTok[128];
  __shared__ float sWt[128];
  u16* sA = smem;
  u16* sB = smem + 128 * 72;

  const int tid = threadIdx.x;
  if (tid < 128) {
    int row = m0 + tid; if (row > cnt - 1) row = cnt - 1;
    sTok[tid] = tlist[e * NTOK + row];
    sWt[tid]  = wlist[e * NTOK + row];
  }

  const int lane = tid & 63;
  const int wv   = tid >> 6;
  const int mo   = (wv & 1) * 64;
  const int no   = (wv >> 1) * 64;
  const int l15  = lane & 15;
  const int quad = lane >> 4;

  floatx4 zero = {0.f, 0.f, 0.f, 0.f};
  floatx4 acc[4][4];
#pragma unroll
  for (int i = 0; i < 4; ++i)
#pragma unroll
    for (int j = 0; j < 4; ++j) acc[i][j] = zero;

  const size_t wbase = (size_t)e * DIM * NFF;

  for (int kc = 0; kc < FFH; kc += 64) {
    for (int c = tid; c < 1024; c += 256) {
      int r = c >> 3, col = (c & 7) * 8;
      int row = m0 + r; if (row > cnt - 1) row = cnt - 1;
      *(uint4*)(sA + r * 72 + col) = *(const uint4*)(H + (size_t)(hrow0 + row) * FFH + kc + col);
    }
    for (int c = tid; c < 2048; c += 256) {
      int r = c >> 4, col = (c & 15) * 4;
      float4 v = *(const float4*)(Wd + wbase + (size_t)(n0 + r) * NFF + ffbase + kc + col);
      uint2 pv; pv.x = pk2(v.x, v.y); pv.y = pk2(v.z, v.w);
      *(uint2*)(sB + r * 72 + col) = pv;
    }
    __syncthreads();
#pragma unroll
    for (int ks = 0; ks < 64; ks += 32) {
      const int kb = ks + quad * 8;
      short8 av[4], bv[4];
#pragma unroll
      for (int i = 0; i < 4; ++i) {
        av[i] = *(const short8*)(sA + (mo + i * 16 + l15) * 72 + kb);
        bv[i] = *(const short8*)(sB + (no + i * 16 + l15) * 72 + kb);
      }
#pragma unroll
      for (int mi = 0; mi < 4; ++mi)
#pragma unroll
        for (int ni = 0; ni < 4; ++ni)
          acc[mi][ni] = __builtin_amdgcn_mfma_f32_16x16x32_bf16(av[mi], bv[ni], acc[mi][ni], 0, 0, 0);
    }
    __syncthreads();
  }

#pragma unroll
  for (int mi = 0; mi < 4; ++mi)
#pragma unroll
    for (int ni = 0; ni < 4; ++ni)
#pragma unroll
      for (int i = 0; i < 4; ++i) {
        int r = mo + mi * 16 + quad * 4 + i;
        int grow = m0 + r;
        if (grow < cnt) {
          int cc = n0 + no + ni * 16 + l15;
          atomicAdd(oacc + (size_t)sTok[r] * DIM + cc, sWt[r] * acc[mi][ni][i]);
        }
      }
}

// ---------------- Residual + LayerNorm (safe in-place when oacc == out) ----------------
__global__ void ln_k(const float* __restrict__ x,
                     const float* __restrict__ oacc,
                     const float* __restrict__ gamma,
                     const float* __restrict__ beta,
                     float* __restrict__ out) {
  const int lane = threadIdx.x & 63;
  const int wv   = threadIdx.x >> 6;
  const int t    = blockIdx.x * 4 + wv;
  const size_t base = (size_t)t * DIM + lane * 16;
  float y[16];
  float s = 0.f, s2 = 0.f;
#pragma unroll
  for (int i = 0; i < 4; ++i) {
    float4 a = ((const float4*)(x + base))[i];
    float4 b = ((const float4*)(oacc + base))[i];
    float c0 = a.x + b.x, c1 = a.y + b.y, c2 = a.z + b.z, c3 = a.w + b.w;
    y[4*i+0] = c0; y[4*i+1] = c1; y[4*i+2] = c2; y[4*i+3] = c3;
    s  += c0 + c1 + c2 + c3;
    s2 += c0*c0 + c1*c1 + c2*c2 + c3*c3;
  }
#pragma unroll
  for (int off = 32; off > 0; off >>= 1) {
    s  += __shfl_xor(s, off, 64);
    s2 += __shfl_xor(s2, off, 64);
  }
  const float mean = s * (1.f / DIM);
  const float var  = s2 * (1.f / DIM) - mean * mean;
  const float rstd = rsqrtf(var + 1e-5f);
#pragma unroll
  for (int i = 0; i < 4; ++i) {
    float4 g  = ((const float4*)(gamma + lane * 16))[i];
    float4 bb = ((const float4*)(beta  + lane * 16))[i];
    float4 o;
    o.x = (y[4*i+0] - mean) * rstd * g.x + bb.x;
    o.y = (y[4*i+1] - mean) * rstd * g.y + bb.y;
    o.z = (y[4*i+2] - mean) * rstd * g.z + bb.z;
    o.w = (y[4*i+3] - mean) * rstd * g.w + bb.w;
    ((float4*)(out + base))[i] = o;
  }
}

// ---------------- Aux loss finalize ----------------
__global__ void aux_k(const int* __restrict__ counts,
                      const float* __restrict__ psum,
                      const float* __restrict__ lse2sum,
                      float* __restrict__ out) {
  if (threadIdx.x == 0 && blockIdx.x == 0) {
    float lb = 0.f;
    for (int e = 0; e < NEXP; ++e) {
      float fi = (float)counts[e] / (float)(NTOK * KSEL);
      float Pi = psum[e] / (float)NTOK;
      lb += fi * Pi;
    }
    lb *= (float)NEXP;
    float z = (*lse2sum / (float)NTOK) * 1e-3f;
    out[(size_t)NTOK * DIM] = 0.01f * (lb + z);
  }
}

extern "C" void kernel_launch(void* const* d_in, const int* in_sizes, int n_in,
                              void* d_out, int out_size, void* d_ws, size_t ws_size,
                              hipStream_t stream) {
  const float* x     = (const float*)d_in[0];
  const float* gW    = (const float*)d_in[1];
  const float* Wg    = (const float*)d_in[2];
  const float* Wu    = (const float*)d_in[3];
  const float* Wd    = (const float*)d_in[4];
  const float* gamma = (const float*)d_in[5];
  const float* beta  = (const float*)d_in[6];
  float* out = (float*)d_out;
  char* ws = (char*)d_ws;

  if (ws_size >= B_NEED) {
    // ---------- BIG path: bf16 weights + global_load_lds staging ----------
    u16*   xb     = (u16*)(ws + B_XB);
    u16*   H      = (u16*)(ws + B_HBUF);
    u16*   wg_bf  = (u16*)(ws + B_WG);
    u16*   wu_bf  = (u16*)(ws + B_WU);
    u16*   wd_bf  = (u16*)(ws + B_WD);
    int*   tlist  = (int*)(ws + B_TL);
    float* wlist  = (float*)(ws + B_WL);
    int*   counts = (int*)(ws + B_CNT);
    float* psum   = (float*)(ws + B_PSUM);
    float* lse2   = (float*)(ws + B_LSE2);
    int*   offs   = (int*)(ws + B_OFFS);

    hipMemsetAsync(ws + B_CNT, 0, 68, stream);                       // counts|psum|lse2
    hipMemsetAsync(d_out, 0, (size_t)NTOK * DIM * 4, stream);        // out doubles as fp32 acc

    router_k<<<NTOK / 4, 256, 0, stream>>>(x, gW, xb, tlist, wlist, counts, psum, lse2);
    offsets_k<<<1, 64, 0, stream>>>(counts, offs);

    const long wn = (long)NEXP * NFF * DIM;   // 33,554,432 per tensor
    cvt_k<<<(int)(wn / 8 / 256), 256, 0, stream>>>(Wg, wg_bf, wn);
    cvt_k<<<(int)(wn / 8 / 256), 256, 0, stream>>>(Wu, wu_bf, wn);
    cvt_k<<<(int)(wn / 8 / 256), 256, 0, stream>>>(Wd, wd_bf, wn);

    for (int q = 0; q < 4; ++q) {
      expA_k<<<dim3(NEXP * 64, FFQ / 128), 256, 0, stream>>>(xb, wg_bf, wu_bf, tlist, counts, offs, H, q * FFQ);
      expB_k<<<dim3(NEXP * 64, DIM / 128), 256, 0, stream>>>(H, wd_bf, tlist, wlist, counts, offs, out, q * FFQ);
    }

    ln_k<<<NTOK / 4, 256, 0, stream>>>(x, out, gamma, beta, out);
    aux_k<<<1, 64, 0, stream>>>(counts, psum, lse2, out);
  } else {
    // ---------- FALLBACK (round-2 proven, needs ~118 MiB) ----------
    u16*   xb     = (u16*)(ws + F_XB);
    u16*   H      = (u16*)(ws + F_HBUF);
    float* oacc   = (float*)(ws + F_OACC);
    int*   tlist  = (int*)(ws + F_TL);
    float* wlist  = (float*)(ws + F_WL);
    int*   counts = (int*)(ws + F_CNT);
    float* psum   = (float*)(ws + F_PSUM);
    float* lse2   = (float*)(ws + F_LSE2);
    int*   offs   = (int*)(ws + F_OFFS);

    hipMemsetAsync(ws + F_CNT, 0, 68, stream);
    hipMemsetAsync(ws + F_OACC, 0, (size_t)NTOK * DIM * 4, stream);

    router_k<<<NTOK / 4, 256, 0, stream>>>(x, gW, xb, tlist, wlist, counts, psum, lse2);
    offsets_k<<<1, 64, 0, stream>>>(counts, offs);

    expertA_fb<<<dim3(NEXP * 64, FFH / 128), 256, 0, stream>>>(xb, Wg, Wu, tlist, counts, offs, H, 0);
    expertB_fb<<<dim3(NEXP * 64, DIM / 128), 256, 0, stream>>>(H, Wd, tlist, wlist, counts, offs, oacc, 0);
    expertA_fb<<<dim3(NEXP * 64, FFH / 128), 256, 0, stream>>>(xb, Wg, Wu, tlist, counts, offs, H, FFH);
    expertB_fb<<<dim3(NEXP * 64, DIM / 128), 256, 0, stream>>>(H, Wd, tlist, wlist, counts, offs, oacc, FFH);

    ln_k<<<NTOK / 4, 256, 0, stream>>>(x, oacc, gamma, beta, out);
    aux_k<<<1, 64, 0, stream>>>(counts, psum, lse2, out);
  }
}

// Round 4
// 1868.472 us; speedup vs baseline: 2.8898x; 1.2868x over previous
//
#include <hip/hip_runtime.h>
#include <hip/hip_bf16.h>

// SparseMoE: router -> bf16 weight pre-convert -> merged-expert MFMA GEMMs with
// global_load_lds staging + XOR-swizzled LDS -> residual+LN.
// B=4 T=2048 D=1024 E=8 FF=4096 K=2 ; N=8192 tokens, expert-rows = 16384.
//
// BIG path ws layout (needs ~240.5 MiB):
//   [0)          x_bf16   16 MiB
//   [16M)        H        16384*1024*2 = 32 MiB (quarter-FF slot rows)
//   [48M)        Wg_bf16  64 MiB
//   [112M)       Wu_bf16  64 MiB
//   [176M)       Wd_bf16  64 MiB
//   [240M)       tlist/wlist/counters/offsets
//   oacc = d_out (fp32 atomicAdd accumulator, LN runs in-place)
// FALLBACK path (ws >= 118 MiB, round-2 proven): fp32 weights converted in-kernel.

#define NTOK 8192
#define DIM  1024
#define NEXP 8
#define NFF  4096
#define FFQ  1024     // quarter of FF per A/B pass (big path)
#define FFH  2048     // half of FF per A/B pass (fallback path)
#define KSEL 2

typedef __attribute__((ext_vector_type(8))) short short8;
typedef __attribute__((ext_vector_type(4))) float floatx4;
typedef unsigned short u16;
typedef unsigned int u32;

// big-path ws offsets (bytes)
#define B_XB    0ull
#define B_HBUF  16777216ull
#define B_WG    50331648ull
#define B_WU    117440512ull
#define B_WD    184549376ull
#define B_TL    251658240ull
#define B_WL    251920384ull
#define B_CNT   252182528ull
#define B_PSUM  252182560ull
#define B_LSE2  252182592ull
#define B_OFFS  252182624ull
#define B_NEED  252182656ull

// fallback ws offsets (round-2 layout)
#define F_XB    0ull
#define F_HBUF  16777216ull
#define F_OACC  83886080ull
#define F_TL    117440512ull
#define F_WL    117702656ull
#define F_CNT   117964800ull
#define F_PSUM  117964832ull
#define F_LSE2  117964864ull
#define F_OFFS  117964896ull

__device__ __forceinline__ u16 f2bf(float f) {
  u32 u = __float_as_uint(f);
  u32 r = u + 0x7fffu + ((u >> 16) & 1u);   // round-to-nearest-even
  return (u16)(r >> 16);
}
__device__ __forceinline__ u32 pk2(float a, float b) {
  return (u32)f2bf(a) | ((u32)f2bf(b) << 16);
}

// async global->LDS DMA, 16 B per lane; LDS base must be wave-uniform.
typedef const __attribute__((address_space(1))) u32 gas_u32;
typedef __attribute__((address_space(3))) u32 las_u32;
__device__ __forceinline__ void dma16(const u16* g, u16* l) {
  __builtin_amdgcn_global_load_lds((gas_u32*)g, (las_u32*)l, 16, 0, 0);
}

// ---------------- Router: logits, softmax, top-2, aux stats, x->bf16 ----------------
__global__ void router_k(const float* __restrict__ x,
                         const float* __restrict__ gW,
                         u16* __restrict__ xb,
                         int* __restrict__ tlist,
                         float* __restrict__ wlist,
                         int* __restrict__ counts,
                         float* __restrict__ psum,
                         float* __restrict__ lse2sum) {
  __shared__ float sp[NEXP];
  __shared__ float slse2;
  if (threadIdx.x < NEXP) sp[threadIdx.x] = 0.f;
  if (threadIdx.x == NEXP) slse2 = 0.f;
  __syncthreads();

  const int lane = threadIdx.x & 63;
  const int wv   = threadIdx.x >> 6;
  const int t    = blockIdx.x * 4 + wv;   // grid = N/4 exactly

  const float* xr = x + (size_t)t * DIM + lane * 16;
  float xv[16];
#pragma unroll
  for (int i = 0; i < 4; ++i) {
    float4 v = ((const float4*)xr)[i];
    xv[4*i+0] = v.x; xv[4*i+1] = v.y; xv[4*i+2] = v.z; xv[4*i+3] = v.w;
  }
  u16* xbp = xb + (size_t)t * DIM + lane * 16;
  uint4 pa, pb;
  pa.x = pk2(xv[0], xv[1]);   pa.y = pk2(xv[2], xv[3]);
  pa.z = pk2(xv[4], xv[5]);   pa.w = pk2(xv[6], xv[7]);
  pb.x = pk2(xv[8], xv[9]);   pb.y = pk2(xv[10], xv[11]);
  pb.z = pk2(xv[12], xv[13]); pb.w = pk2(xv[14], xv[15]);
  ((uint4*)xbp)[0] = pa;
  ((uint4*)xbp)[1] = pb;

  float lg[NEXP];
#pragma unroll
  for (int e = 0; e < NEXP; ++e) {
    const float* wr = gW + (size_t)e * DIM + lane * 16;
    float s = 0.f;
#pragma unroll
    for (int i = 0; i < 4; ++i) {
      float4 v = ((const float4*)wr)[i];
      s = fmaf(xv[4*i+0], v.x, s);
      s = fmaf(xv[4*i+1], v.y, s);
      s = fmaf(xv[4*i+2], v.z, s);
      s = fmaf(xv[4*i+3], v.w, s);
    }
    lg[e] = s;
  }
#pragma unroll
  for (int off = 32; off > 0; off >>= 1) {
#pragma unroll
    for (int e = 0; e < NEXP; ++e)
      lg[e] += __shfl_xor(lg[e], off, 64);
  }
  float mx = lg[0];
#pragma unroll
  for (int e = 1; e < NEXP; ++e) mx = fmaxf(mx, lg[e]);
  float p[NEXP];
  float se = 0.f;
#pragma unroll
  for (int e = 0; e < NEXP; ++e) { p[e] = expf(lg[e] - mx); se += p[e]; }
  float inv = 1.f / se;
#pragma unroll
  for (int e = 0; e < NEXP; ++e) p[e] *= inv;
  float lse = mx + logf(se);

  if (lane == 0) {
    int i0 = 0;
#pragma unroll
    for (int e = 1; e < NEXP; ++e) if (p[e] > p[i0]) i0 = e;
    int i1 = (i0 == 0) ? 1 : 0;
#pragma unroll
    for (int e = 0; e < NEXP; ++e) if (e != i0 && p[e] > p[i1]) i1 = e;
    float v0 = p[i0], v1 = p[i1];
    float s2 = v0 + v1 + 1e-6f;
    int pos0 = atomicAdd(&counts[i0], 1);
    tlist[i0 * NTOK + pos0] = t;
    wlist[i0 * NTOK + pos0] = v0 / s2;
    int pos1 = atomicAdd(&counts[i1], 1);
    tlist[i1 * NTOK + pos1] = t;
    wlist[i1 * NTOK + pos1] = v1 / s2;
#pragma unroll
    for (int e = 0; e < NEXP; ++e) atomicAdd(&sp[e], p[e]);
    atomicAdd(&slse2, lse * lse);
  }
  __syncthreads();
  if (threadIdx.x < NEXP) atomicAdd(&psum[threadIdx.x], sp[threadIdx.x]);
  if (threadIdx.x == NEXP) atomicAdd(lse2sum, slse2);
}

// ---------------- offsets: prefix-sum of counts ----------------
__global__ void offsets_k(const int* __restrict__ counts, int* __restrict__ offsets) {
  if (threadIdx.x == 0 && blockIdx.x == 0) {
    int s = 0;
    for (int e = 0; e < NEXP; ++e) { offsets[e] = s; s += counts[e]; }
  }
}

// ---------------- fp32 -> bf16 bulk convert (one-time, memory-bound) ----------------
__global__ void cvt_k(const float* __restrict__ s, u16* __restrict__ d, long n) {
  long i = ((long)blockIdx.x * 256 + threadIdx.x) * 8;
  if (i >= n) return;
  float4 a = *(const float4*)(s + i);
  float4 b = *(const float4*)(s + i + 4);
  uint4 o;
  o.x = pk2(a.x, a.y); o.y = pk2(a.z, a.w);
  o.z = pk2(b.x, b.y); o.w = pk2(b.z, b.w);
  *(uint4*)(d + i) = o;
}

// ================= BIG PATH =================
// LDS tiles are XOR-chunk-swizzled: LDS(row, chunk) holds global chunk (chunk^(row&7)).
// DMA side: lane fetches global chunk ((lane&7)^srow); read side: chunk' = c ^ (row&7).
// Fragment reads then hit exactly 2 lanes/bank (free, m136).

// Pass A: H = silu(X Wg^T) * (X Wu^T), quarter of FF.
// Block = 128 tokens x 64 ff. B-tile (128 rows) interleaves Wg/Wu in 16-row groups:
// B-row r -> h=r>>4, group p=h>>1, type=h&1 (0=Wg,1=Wu), ffrow = nb + p*16 + (r&15).
// Wave (wv): token-half th=wv&1 (rows th*64..), B-half bh=wv>>1 (B-rows bh*64..).
// acc[mi][ni]: ni even = gate, ni odd = up, same ff cols -> lane-aligned silu epilogue.
__global__ __launch_bounds__(256, 3) void expA_k(
    const u16* __restrict__ xb,
    const u16* __restrict__ Wg,
    const u16* __restrict__ Wu,
    const int* __restrict__ tlist,
    const int* __restrict__ counts,
    const int* __restrict__ offsets,
    u16* __restrict__ H,          // [16384, FFQ] compact slot rows
    int ffbase) {
  const int e   = blockIdx.x >> 6;
  const int m0  = (blockIdx.x & 63) * 128;
  const int cnt = counts[e];
  if (m0 >= cnt) return;
  const int nb  = blockIdx.y * 64;       // ff base within quarter
  const int hrow0 = offsets[e];

  __shared__ u16 smem[2 * 128 * 64];     // A | B(interleaved W) tiles, 32 KB
  u16* sA = smem;
  u16* sB = smem + 8192;

  const int tid  = threadIdx.x;
  const int lane = tid & 63;
  const int wv   = tid >> 6;
  const int l15  = lane & 15;
  const int quad = lane >> 4;
  const int mo   = (wv & 1) * 64;        // token rows
  const int bh   = wv >> 1;
  const int no   = bh * 64;              // B rows
  const int srow = lane >> 3;            // 0..7 within DMA group
  const int cswz = (lane & 7) ^ srow;    // swizzled global chunk this lane fetches

  // per-lane global bases (fixed across K)
  const u16* gA[4];
  const u16* gB[4];
#pragma unroll
  for (int j = 0; j < 4; ++j) {
    int r = 32 * wv + 8 * j + srow;      // tile row 0..127
    int row = m0 + r; if (row > cnt - 1) row = cnt - 1;   // clamp: dup rows, masked at store
    int tok = tlist[e * NTOK + row];
    gA[j] = xb + (size_t)tok * DIM + cswz * 8;
    // B-tile row r: type=(j>>1)&1, ff = ffbase + nb + wv*16 + 8*(j&1) + srow
    const u16* src = ((j >> 1) & 1) ? Wu : Wg;
    int ff = ffbase + nb + (wv & 3) * 16 + 8 * (j & 1) + srow;
    gB[j] = src + (size_t)e * NFF * DIM + (size_t)ff * DIM + cswz * 8;
  }

  floatx4 zero = {0.f, 0.f, 0.f, 0.f};
  floatx4 acc[4][4];
#pragma unroll
  for (int i = 0; i < 4; ++i)
#pragma unroll
    for (int j = 0; j < 4; ++j) acc[i][j] = zero;

  for (int kc = 0; kc < DIM; kc += 64) {
#pragma unroll
    for (int j = 0; j < 4; ++j) {
      u16* lb = smem + (32 * wv + 8 * j) * 64;   // wave-uniform
      dma16(gA[j] + kc, lb);
      dma16(gB[j] + kc, lb + 8192);
    }
    __syncthreads();   // drains vmcnt (DMA) before reads
#pragma unroll
    for (int ks = 0; ks < 64; ks += 32) {
      const int c0 = (ks >> 3) + quad;           // global 16B-chunk index of this frag
      short8 av[4], bv[4];
#pragma unroll
      for (int i = 0; i < 4; ++i) {
        int ra = mo + i * 16 + l15;
        int rb = no + i * 16 + l15;
        av[i] = *(const short8*)(sA + ra * 64 + ((c0 ^ (ra & 7)) * 8));
        bv[i] = *(const short8*)(sB + rb * 64 + ((c0 ^ (rb & 7)) * 8));
      }
#pragma unroll
      for (int mi = 0; mi < 4; ++mi)
#pragma unroll
        for (int ni = 0; ni < 4; ++ni)
          acc[mi][ni] = __builtin_amdgcn_mfma_f32_16x16x32_bf16(av[mi], bv[ni], acc[mi][ni], 0, 0, 0);
    }
    __syncthreads();   // all reads done before next DMA overwrites
  }

  // silu(g)*u -> bf16 via LDS (stride 72) then vectorized store of 128x64 tile
  u16* sH = smem;      // 128*72*2 = 18.4 KB
#pragma unroll
  for (int mi = 0; mi < 4; ++mi)
#pragma unroll
    for (int p2 = 0; p2 < 2; ++p2)
#pragma unroll
      for (int i = 0; i < 4; ++i) {
        float g = acc[mi][2 * p2 + 0][i];
        float u = acc[mi][2 * p2 + 1][i];
        float h = (g / (1.f + __expf(-g))) * u;
        int r  = mo + mi * 16 + quad * 4 + i;    // C/D: row = quad*4+reg
        int cc = (2 * bh + p2) * 16 + l15;       // local ff col 0..63
        sH[r * 72 + cc] = f2bf(h);
      }
  __syncthreads();
  for (int c = tid; c < 1024; c += 256) {
    int r = c >> 3, col = (c & 7) * 8;
    int row = m0 + r;
    if (row < cnt)
      *(uint4*)(H + (size_t)(hrow0 + row) * FFQ + nb + col) = *(const uint4*)(sH + r * 72 + col);
  }
}

// Pass B: oacc[tok] += gate * (H Wd^T), quarter-FF K. 128x128 tile, swizzled LDS.
__global__ __launch_bounds__(256, 4) void expB_k(
    const u16* __restrict__ H,           // [16384, FFQ]
    const u16* __restrict__ Wd,
    const int* __restrict__ tlist,
    const float* __restrict__ wlist,
    const int* __restrict__ counts,
    const int* __restrict__ offsets,
    float* __restrict__ oacc,
    int ffbase) {
  const int e   = blockIdx.x >> 6;
  const int m0  = (blockIdx.x & 63) * 128;
  const int cnt = counts[e];
  if (m0 >= cnt) return;
  const int n0 = blockIdx.y * 128;
  const int hrow0 = offsets[e];

  __shared__ u16 smem2[2 * 128 * 64];
  __shared__ int   sTok[128];
  __shared__ float sWt[128];
  u16* sA = smem2;
  u16* sB = smem2 + 8192;

  const int tid = threadIdx.x;
  if (tid < 128) {
    int row = m0 + tid; if (row > cnt - 1) row = cnt - 1;
    sTok[tid] = tlist[e * NTOK + row];
    sWt[tid]  = wlist[e * NTOK + row];
  }

  const int lane = tid & 63;
  const int wv   = tid >> 6;
  const int l15  = lane & 15;
  const int quad = lane >> 4;
  const int mo   = (wv & 1) * 64;
  const int no   = (wv >> 1) * 64;
  const int srow = lane >> 3;
  const int cswz = (lane & 7) ^ srow;

  const u16* gH[4];
  const u16* gB[4];
#pragma unroll
  for (int j = 0; j < 4; ++j) {
    int r = 32 * wv + 8 * j + srow;
    int row = m0 + r; if (row > cnt - 1) row = cnt - 1;
    gH[j] = H + (size_t)(hrow0 + row) * FFQ + cswz * 8;
    gB[j] = Wd + (size_t)e * DIM * NFF + (size_t)(n0 + r) * NFF + ffbase + cswz * 8;
  }

  floatx4 zero = {0.f, 0.f, 0.f, 0.f};
  floatx4 acc[4][4];
#pragma unroll
  for (int i = 0; i < 4; ++i)
#pragma unroll
    for (int j = 0; j < 4; ++j) acc[i][j] = zero;

  for (int kc = 0; kc < FFQ; kc += 64) {
#pragma unroll
    for (int j = 0; j < 4; ++j) {
      u16* lb = smem2 + (32 * wv + 8 * j) * 64;
      dma16(gH[j] + kc, lb);
      dma16(gB[j] + kc, lb + 8192);
    }
    __syncthreads();
#pragma unroll
    for (int ks = 0; ks < 64; ks += 32) {
      const int c0 = (ks >> 3) + quad;
      short8 av[4], bv[4];
#pragma unroll
      for (int i = 0; i < 4; ++i) {
        int ra = mo + i * 16 + l15;
        int rb = no + i * 16 + l15;
        av[i] = *(const short8*)(sA + ra * 64 + ((c0 ^ (ra & 7)) * 8));
        bv[i] = *(const short8*)(sB + rb * 64 + ((c0 ^ (rb & 7)) * 8));
      }
#pragma unroll
      for (int mi = 0; mi < 4; ++mi)
#pragma unroll
        for (int ni = 0; ni < 4; ++ni)
          acc[mi][ni] = __builtin_amdgcn_mfma_f32_16x16x32_bf16(av[mi], bv[ni], acc[mi][ni], 0, 0, 0);
    }
    __syncthreads();
  }

  // scatter-accumulate: atomicAdd (token can be hit by 2 experts per dispatch)
#pragma unroll
  for (int mi = 0; mi < 4; ++mi)
#pragma unroll
    for (int ni = 0; ni < 4; ++ni)
#pragma unroll
      for (int i = 0; i < 4; ++i) {
        int r = mo + mi * 16 + quad * 4 + i;
        int grow = m0 + r;
        if (grow < cnt) {
          int cc = n0 + no + ni * 16 + l15;
          atomicAdd(oacc + (size_t)sTok[r] * DIM + cc, sWt[r] * acc[mi][ni][i]);
        }
      }
}

// ================= FALLBACK PATH (round-2 proven kernels, fp32 weights) =================

__global__ __launch_bounds__(256, 2) void expertA_fb(
    const u16* __restrict__ xb,
    const float* __restrict__ Wg,
    const float* __restrict__ Wu,
    const int* __restrict__ tlist,
    const int* __restrict__ counts,
    const int* __restrict__ offsets,
    u16* __restrict__ H,         // [16384, FFH]
    int ffbase) {
  const int e   = blockIdx.x >> 6;
  const int m0  = (blockIdx.x & 63) * 128;
  const int cnt = counts[e];
  if (m0 >= cnt) return;
  const int n0 = ffbase + blockIdx.y * 128;
  const int hc0 = blockIdx.y * 128;
  const int hrow0 = offsets[e];

  __shared__ u16 smem[3 * 128 * 72];
  u16* sA = smem;
  u16* sG = smem + 128 * 72;
  u16* sU = smem + 2 * 128 * 72;

  const int tid  = threadIdx.x;
  const int lane = tid & 63;
  const int wv   = tid >> 6;
  const int mo   = (wv & 1) * 64;
  const int no   = (wv >> 1) * 64;
  const int l15  = lane & 15;
  const int quad = lane >> 4;

  floatx4 zero = {0.f, 0.f, 0.f, 0.f};
  floatx4 accG[4][4], accU[4][4];
#pragma unroll
  for (int i = 0; i < 4; ++i)
#pragma unroll
    for (int j = 0; j < 4; ++j) { accG[i][j] = zero; accU[i][j] = zero; }

  const size_t wbase = (size_t)e * NFF * DIM;
  const int* tl = tlist + e * NTOK;

  for (int kc = 0; kc < DIM; kc += 64) {
    for (int c = tid; c < 1024; c += 256) {
      int r = c >> 3, col = (c & 7) * 8;
      int row = m0 + r; if (row > cnt - 1) row = cnt - 1;
      int tok = tl[row];
      *(uint4*)(sA + r * 72 + col) = *(const uint4*)(xb + (size_t)tok * DIM + kc + col);
    }
    for (int c = tid; c < 2048; c += 256) {
      int r = c >> 4, col = (c & 15) * 4;
      size_t gi = wbase + (size_t)(n0 + r) * DIM + kc + col;
      float4 g = *(const float4*)(Wg + gi);
      float4 u = *(const float4*)(Wu + gi);
      uint2 pg; pg.x = pk2(g.x, g.y); pg.y = pk2(g.z, g.w);
      uint2 pu; pu.x = pk2(u.x, u.y); pu.y = pk2(u.z, u.w);
      *(uint2*)(sG + r * 72 + col) = pg;
      *(uint2*)(sU + r * 72 + col) = pu;
    }
    __syncthreads();
#pragma unroll
    for (int ks = 0; ks < 64; ks += 32) {
      const int kb = ks + quad * 8;
      short8 av[4], bg[4], bu[4];
#pragma unroll
      for (int i = 0; i < 4; ++i) {
        av[i] = *(const short8*)(sA + (mo + i * 16 + l15) * 72 + kb);
        bg[i] = *(const short8*)(sG + (no + i * 16 + l15) * 72 + kb);
        bu[i] = *(const short8*)(sU + (no + i * 16 + l15) * 72 + kb);
      }
#pragma unroll
      for (int mi = 0; mi < 4; ++mi)
#pragma unroll
        for (int ni = 0; ni < 4; ++ni) {
          accG[mi][ni] = __builtin_amdgcn_mfma_f32_16x16x32_bf16(av[mi], bg[ni], accG[mi][ni], 0, 0, 0);
          accU[mi][ni] = __builtin_amdgcn_mfma_f32_16x16x32_bf16(av[mi], bu[ni], accU[mi][ni], 0, 0, 0);
        }
    }
    __syncthreads();
  }

  u16* sH = smem;
#pragma unroll
  for (int mi = 0; mi < 4; ++mi)
#pragma unroll
    for (int ni = 0; ni < 4; ++ni)
#pragma unroll
      for (int i = 0; i < 4; ++i) {
        float g = accG[mi][ni][i];
        float u = accU[mi][ni][i];
        float h = (g / (1.f + __expf(-g))) * u;
        int r  = mo + mi * 16 + quad * 4 + i;
        int cc = no + ni * 16 + l15;
        sH[r * 136 + cc] = f2bf(h);
      }
  __syncthreads();
  for (int c = tid; c < 2048; c += 256) {
    int r = c >> 4, col = (c & 15) * 8;
    int row = m0 + r;
    if (row < cnt)
      *(uint4*)(H + (size_t)(hrow0 + row) * FFH + hc0 + col) = *(const uint4*)(sH + r * 136 + col);
  }
}

__global__ __launch_bounds__(256, 2) void expertB_fb(
    const u16* __restrict__ H,          // [16384, FFH]
    const float* __restrict__ Wd,
    const int* __restrict__ tlist,
    const float* __restrict__ wlist,
    const int* __restrict__ counts,
    const int* __restrict__ offsets,
    float* __restrict__ oacc,
    int ffbase) {
  const int e   = blockIdx.x >> 6;
  const int m0  = (blockIdx.x & 63) * 128;
  const int cnt = counts[e];
  if (m0 >= cnt) return;
  const int n0 = blockIdx.y * 128;
  const int hrow0 = offsets[e];

  __shared__ u16 smem[2 * 128 * 72];
  __shared__ int   sTok[128];
  __shared__ float sWt[128];
  u16* sA = smem;
  u16* sB = smem + 128 * 72;

  const int tid = threadIdx.x;
  if (tid < 128) {
    int row = m0 + tid; if (row > cnt - 1) row = cnt - 1;
    sTok[tid] = tlist[e * NTOK + row];
    sWt[tid]  = wlist[e * NTOK + row];
  }

  const int lane = tid & 63;
  const int wv   = tid >> 6;
  const int mo   = (wv & 1) * 64;
  const int no   = (wv >> 1) * 64;
  const int l15  = lane & 15;
  const int quad = lane >> 4;

  floatx4 zero = {0.f, 0.f, 0.f, 0.f};
  floatx4 acc[4][4];
#pragma unroll
  for (int i = 0; i < 4; ++i)
#pragma unroll
    for (int j = 0; j < 4; ++j) acc[i][j] = zero;

  const size_t wbase = (size_t)e * DIM * NFF;

  for (int kc = 0; kc < FFH; kc += 64) {
    for (int c = tid; c < 1024; c += 256) {
      int r = c >> 3, col = (c & 7) * 8;
      int row = m0 + r; if (row > cnt - 1) row = cnt - 1;
      *(uint4*)(sA + r * 72 + col) = *(const uint4*)(H + (size_t)(hrow0 + row) * FFH + kc + col);
    }
    for (int c = tid; c < 2048; c += 256) {
      int r = c >> 4, col = (c & 15) * 4;
      float4 v = *(const float4*)(Wd + wbase + (size_t)(n0 + r) * NFF + ffbase + kc + col);
      uint2 pv; pv.x = pk2(v.x, v.y); pv.y = pk2(v.z, v.w);
      *(uint2*)(sB + r * 72 + col) = pv;
    }
    __syncthreads();
#pragma unroll
    for (int ks = 0; ks < 64; ks += 32) {
      const int kb = ks + quad * 8;
      short8 av[4], bv[4];
#pragma unroll
      for (int i = 0; i < 4; ++i) {
        av[i] = *(const short8*)(sA + (mo + i * 16 + l15) * 72 + kb);
        bv[i] = *(const short8*)(sB + (no + i * 16 + l15) * 72 + kb);
      }
#pragma unroll
      for (int mi = 0; mi < 4; ++mi)
#pragma unroll
        for (int ni = 0; ni < 4; ++ni)
          acc[mi][ni] = __builtin_amdgcn_mfma_f32_16x16x32_bf16(av[mi], bv[ni], acc[mi][ni], 0, 0, 0);
    }
    __syncthreads();
  }

#pragma unroll
  for (int mi = 0; mi < 4; ++mi)
#pragma unroll
    for (int ni = 0; ni < 4; ++ni)
#pragma unroll
      for (int i = 0; i < 4; ++i) {
        int r = mo + mi * 16 + quad * 4 + i;
        int grow = m0 + r;
        if (grow < cnt) {
          int cc = n0 + no + ni * 16 + l15;
          atomicAdd(oacc + (size_t)sTok[r] * DIM + cc, sWt[r] * acc[mi][ni][i]);
        }
      }
}

// ---------------- Residual + LayerNorm (safe in-place when oacc == out) ----------------
__global__ void ln_k(const float* __restrict__ x,
                     const float* __restrict__ oacc,
                     const float* __restrict__ gamma,
                     const float* __restrict__ beta,
                     float* __restrict__ out) {
  const int lane = threadIdx.x & 63;
  const int wv   = threadIdx.x >> 6;
  const int t    = blockIdx.x * 4 + wv;
  const size_t base = (size_t)t * DIM + lane * 16;
  float y[16];
  float s = 0.f, s2 = 0.f;
#pragma unroll
  for (int i = 0; i < 4; ++i) {
    float4 a = ((const float4*)(x + base))[i];
    float4 b = ((const float4*)(oacc + base))[i];
    float c0 = a.x + b.x, c1 = a.y + b.y, c2 = a.z + b.z, c3 = a.w + b.w;
    y[4*i+0] = c0; y[4*i+1] = c1; y[4*i+2] = c2; y[4*i+3] = c3;
    s  += c0 + c1 + c2 + c3;
    s2 += c0*c0 + c1*c1 + c2*c2 + c3*c3;
  }
#pragma unroll
  for (int off = 32; off > 0; off >>= 1) {
    s  += __shfl_xor(s, off, 64);
    s2 += __shfl_xor(s2, off, 64);
  }
  const float mean = s * (1.f / DIM);
  const float var  = s2 * (1.f / DIM) - mean * mean;
  const float rstd = rsqrtf(var + 1e-5f);
#pragma unroll
  for (int i = 0; i < 4; ++i) {
    float4 g  = ((const float4*)(gamma + lane * 16))[i];
    float4 bb = ((const float4*)(beta  + lane * 16))[i];
    float4 o;
    o.x = (y[4*i+0] - mean) * rstd * g.x + bb.x;
    o.y = (y[4*i+1] - mean) * rstd * g.y + bb.y;
    o.z = (y[4*i+2] - mean) * rstd * g.z + bb.z;
    o.w = (y[4*i+3] - mean) * rstd * g.w + bb.w;
    ((float4*)(out + base))[i] = o;
  }
}

// ---------------- Aux loss finalize ----------------
__global__ void aux_k(const int* __restrict__ counts,
                      const float* __restrict__ psum,
                      const float* __restrict__ lse2sum,
                      float* __restrict__ out) {
  if (threadIdx.x == 0 && blockIdx.x == 0) {
    float lb = 0.f;
    for (int e = 0; e < NEXP; ++e) {
      float fi = (float)counts[e] / (float)(NTOK * KSEL);
      float Pi = psum[e] / (float)NTOK;
      lb += fi * Pi;
    }
    lb *= (float)NEXP;
    float z = (*lse2sum / (float)NTOK) * 1e-3f;
    out[(size_t)NTOK * DIM] = 0.01f * (lb + z);
  }
}

extern "C" void kernel_launch(void* const* d_in, const int* in_sizes, int n_in,
                              void* d_out, int out_size, void* d_ws, size_t ws_size,
                              hipStream_t stream) {
  const float* x     = (const float*)d_in[0];
  const float* gW    = (const float*)d_in[1];
  const float* Wg    = (const float*)d_in[2];
  const float* Wu    = (const float*)d_in[3];
  const float* Wd    = (const float*)d_in[4];
  const float* gamma = (const float*)d_in[5];
  const float* beta  = (const float*)d_in[6];
  float* out = (float*)d_out;
  char* ws = (char*)d_ws;

  if (ws_size >= B_NEED) {
    // ---------- BIG path: bf16 weights + global_load_lds staging ----------
    u16*   xb     = (u16*)(ws + B_XB);
    u16*   H      = (u16*)(ws + B_HBUF);
    u16*   wg_bf  = (u16*)(ws + B_WG);
    u16*   wu_bf  = (u16*)(ws + B_WU);
    u16*   wd_bf  = (u16*)(ws + B_WD);
    int*   tlist  = (int*)(ws + B_TL);
    float* wlist  = (float*)(ws + B_WL);
    int*   counts = (int*)(ws + B_CNT);
    float* psum   = (float*)(ws + B_PSUM);
    float* lse2   = (float*)(ws + B_LSE2);
    int*   offs   = (int*)(ws + B_OFFS);

    hipMemsetAsync(ws + B_CNT, 0, 68, stream);                       // counts|psum|lse2
    hipMemsetAsync(d_out, 0, (size_t)NTOK * DIM * 4, stream);        // out doubles as fp32 acc

    router_k<<<NTOK / 4, 256, 0, stream>>>(x, gW, xb, tlist, wlist, counts, psum, lse2);
    offsets_k<<<1, 64, 0, stream>>>(counts, offs);

    const long wn = (long)NEXP * NFF * DIM;   // 33,554,432 per tensor
    cvt_k<<<(int)(wn / 8 / 256), 256, 0, stream>>>(Wg, wg_bf, wn);
    cvt_k<<<(int)(wn / 8 / 256), 256, 0, stream>>>(Wu, wu_bf, wn);
    cvt_k<<<(int)(wn / 8 / 256), 256, 0, stream>>>(Wd, wd_bf, wn);

    for (int q = 0; q < 4; ++q) {
      expA_k<<<dim3(NEXP * 64, FFQ / 64), 256, 0, stream>>>(xb, wg_bf, wu_bf, tlist, counts, offs, H, q * FFQ);
      expB_k<<<dim3(NEXP * 64, DIM / 128), 256, 0, stream>>>(H, wd_bf, tlist, wlist, counts, offs, out, q * FFQ);
    }

    ln_k<<<NTOK / 4, 256, 0, stream>>>(x, out, gamma, beta, out);
    aux_k<<<1, 64, 0, stream>>>(counts, psum, lse2, out);
  } else {
    // ---------- FALLBACK (round-2 proven, needs ~118 MiB) ----------
    u16*   xb     = (u16*)(ws + F_XB);
    u16*   H      = (u16*)(ws + F_HBUF);
    float* oacc   = (float*)(ws + F_OACC);
    int*   tlist  = (int*)(ws + F_TL);
    float* wlist  = (float*)(ws + F_WL);
    int*   counts = (int*)(ws + F_CNT);
    float* psum   = (float*)(ws + F_PSUM);
    float* lse2   = (float*)(ws + F_LSE2);
    int*   offs   = (int*)(ws + F_OFFS);

    hipMemsetAsync(ws + F_CNT, 0, 68, stream);
    hipMemsetAsync(ws + F_OACC, 0, (size_t)NTOK * DIM * 4, stream);

    router_k<<<NTOK / 4, 256, 0, stream>>>(x, gW, xb, tlist, wlist, counts, psum, lse2);
    offsets_k<<<1, 64, 0, stream>>>(counts, offs);

    expertA_fb<<<dim3(NEXP * 64, FFH / 128), 256, 0, stream>>>(xb, Wg, Wu, tlist, counts, offs, H, 0);
    expertB_fb<<<dim3(NEXP * 64, DIM / 128), 256, 0, stream>>>(H, Wd, tlist, wlist, counts, offs, oacc, 0);
    expertA_fb<<<dim3(NEXP * 64, FFH / 128), 256, 0, stream>>>(xb, Wg, Wu, tlist, counts, offs, H, FFH);
    expertB_fb<<<dim3(NEXP * 64, DIM / 128), 256, 0, stream>>>(H, Wd, tlist, wlist, counts, offs, oacc, FFH);

    ln_k<<<NTOK / 4, 256, 0, stream>>>(x, oacc, gamma, beta, out);
    aux_k<<<1, 64, 0, stream>>>(counts, psum, lse2, out);
  }
}